// Round 1
// baseline (5210.313 us; speedup 1.0000x reference)
//
#include <hip/hip_runtime.h>

#define NB 2
#define SEQN 384
#define NS 1537
#define NH 8
#define H2N 16
#define QKD 48
#define NM (NB*NS)
#define DFF 1536
#define EPS1 1.1920929e-07f
#define SCAL (1.0f/48.0f)
#define NEG_INF (-__builtin_huge_valf())

typedef __bf16 bf16x8 __attribute__((ext_vector_type(8)));
typedef float f32x4 __attribute__((ext_vector_type(4)));

__device__ __forceinline__ unsigned short f2bf(float f) {
    unsigned int u = __builtin_bit_cast(unsigned int, f);
    u += 0x7FFFu + ((u >> 16) & 1u);
    return (unsigned short)(u >> 16);
}
__device__ __forceinline__ float bf2f(unsigned short h) {
    unsigned int u = ((unsigned int)h) << 16;
    return __builtin_bit_cast(float, u);
}

// ---------------- transpose weights (KxN f32 -> NxK bf16 hi[/lo]) ----------------
__global__ void transpose_split(const float* __restrict__ w, unsigned short* __restrict__ hi,
                                unsigned short* __restrict__ lo, int K, int N) {
    __shared__ float tile[32][33];
    int k0 = blockIdx.x * 32, n0 = blockIdx.y * 32;
    int tx = threadIdx.x & 31, ty4 = (threadIdx.x >> 5) * 4;
    for (int i = 0; i < 4; i++) {
        int k = k0 + ty4 + i, n = n0 + tx;
        tile[ty4 + i][tx] = (k < K && n < N) ? w[(size_t)k * N + n] : 0.f;
    }
    __syncthreads();
    for (int i = 0; i < 4; i++) {
        int n = n0 + ty4 + i, k = k0 + tx;
        if (n < N && k < K) {
            float v = tile[tx][ty4 + i];
            unsigned short hb = f2bf(v);
            size_t o = (size_t)n * K + k;
            hi[o] = hb;
            if (lo) lo[o] = f2bf(v - bf2f(hb));
        }
    }
}

// ---------------- lambda scalar ----------------
__global__ void lam_kernel(const float* q1, const float* k1, const float* q2, const float* k2,
                           float* out) {
    int t = threadIdx.x;
    float p1 = 0.f, p2 = 0.f;
    if (t < 32) { p1 = q1[t] * k1[t]; p2 = q2[t] * k2[t]; }
    for (int o = 1; o < 32; o <<= 1) { p1 += __shfl_xor(p1, o); p2 += __shfl_xor(p2, o); }
    if (t == 0) out[0] = expf(p1) - expf(p2) + 0.2f;
}

// ---------------- rmsnorm (f32 in, bf16 hi[/lo] out) ----------------
__global__ __launch_bounds__(256) void rmsnorm_k(const float* __restrict__ in,
    const float* __restrict__ w, unsigned short* __restrict__ hi, unsigned short* __restrict__ lo,
    int in_stride, int C, float eps) {
    int row = blockIdx.x;
    const float* x = in + (size_t)row * in_stride;
    float ss = 0.f;
    for (int j = threadIdx.x; j < C; j += 256) { float v = x[j]; ss += v * v; }
    for (int o = 1; o < 64; o <<= 1) ss += __shfl_xor(ss, o);
    __shared__ float red[4];
    if ((threadIdx.x & 63) == 0) red[threadIdx.x >> 6] = ss;
    __syncthreads();
    ss = red[0] + red[1] + red[2] + red[3];
    float rs = rsqrtf(ss / (float)C + eps);
    for (int j = threadIdx.x; j < C; j += 256) {
        float y = x[j] * rs * w[j];
        unsigned short hb = f2bf(y);
        hi[(size_t)row * C + j] = hb;
        if (lo) lo[(size_t)row * C + j] = f2bf(y - bf2f(hb));
    }
}

// ---------------- single-bf16 GEMM: C(MxN) = A(MxK) * Bt(NxK)^T [+res] ----------------
__global__ __launch_bounds__(256) void gemm_single(const unsigned short* __restrict__ A,
    const unsigned short* __restrict__ Bt, float* __restrict__ C_, const float* __restrict__ res,
    int M, int N, int K) {
    __shared__ unsigned short As[64][32];
    __shared__ unsigned short Bs[64][32];
    int m0 = blockIdx.x * 64, n0 = blockIdx.y * 64;
    int tid = threadIdx.x;
    int lane = tid & 63, wid = tid >> 6;
    int wr = wid >> 1, wc = wid & 1;
    int r = lane & 15, g = lane >> 4;
    int lrow = tid >> 2, lk = (tid & 3) * 8;
    f32x4 acc[2][2] = {};
    int arow = m0 + lrow, brow = n0 + lrow;
    bool aok = arow < M, bok = brow < N;
    size_t aoff = (size_t)arow * K + lk, boff = (size_t)brow * K + lk;
    for (int k0 = 0; k0 < K; k0 += 32) {
        uint4 av = {0,0,0,0}, bv = {0,0,0,0};
        if (aok) av = *(const uint4*)(A + aoff + k0);
        if (bok) bv = *(const uint4*)(Bt + boff + k0);
        __syncthreads();
        *(uint4*)&As[lrow][lk] = av;
        *(uint4*)&Bs[lrow][lk] = bv;
        __syncthreads();
        bf16x8 a0 = *(const bf16x8*)&As[wr * 32 + r][g * 8];
        bf16x8 a1 = *(const bf16x8*)&As[wr * 32 + 16 + r][g * 8];
        bf16x8 b0 = *(const bf16x8*)&Bs[wc * 32 + r][g * 8];
        bf16x8 b1 = *(const bf16x8*)&Bs[wc * 32 + 16 + r][g * 8];
        acc[0][0] = __builtin_amdgcn_mfma_f32_16x16x32_bf16(a0, b0, acc[0][0], 0, 0, 0);
        acc[0][1] = __builtin_amdgcn_mfma_f32_16x16x32_bf16(a0, b1, acc[0][1], 0, 0, 0);
        acc[1][0] = __builtin_amdgcn_mfma_f32_16x16x32_bf16(a1, b0, acc[1][0], 0, 0, 0);
        acc[1][1] = __builtin_amdgcn_mfma_f32_16x16x32_bf16(a1, b1, acc[1][1], 0, 0, 0);
    }
    for (int i = 0; i < 2; i++) for (int j = 0; j < 2; j++) {
        int col = n0 + wc * 32 + j * 16 + r;
        if (col >= N) continue;
        for (int e = 0; e < 4; e++) {
            int row = m0 + wr * 32 + i * 16 + g * 4 + e;
            if (row >= M) continue;
            float v = acc[i][j][e];
            if (res) v += res[(size_t)row * N + col];
            C_[(size_t)row * N + col] = v;
        }
    }
}

// ---------------- split-bf16 (hi+lo, 3xMFMA) GEMM: near-fp32 precision ----------------
__global__ __launch_bounds__(256) void gemm_x3(const unsigned short* __restrict__ Ah,
    const unsigned short* __restrict__ Al, const unsigned short* __restrict__ Bh,
    const unsigned short* __restrict__ Bl, float* __restrict__ C_, int M, int N, int K) {
    __shared__ unsigned short AsH[64][32], AsL[64][32], BsH[64][32], BsL[64][32];
    int m0 = blockIdx.x * 64, n0 = blockIdx.y * 64;
    int tid = threadIdx.x;
    int lane = tid & 63, wid = tid >> 6;
    int wr = wid >> 1, wc = wid & 1;
    int r = lane & 15, g = lane >> 4;
    int lrow = tid >> 2, lk = (tid & 3) * 8;
    f32x4 acc[2][2] = {};
    int arow = m0 + lrow, brow = n0 + lrow;
    bool aok = arow < M, bok = brow < N;
    size_t aoff = (size_t)arow * K + lk, boff = (size_t)brow * K + lk;
    for (int k0 = 0; k0 < K; k0 += 32) {
        uint4 avh = {0,0,0,0}, avl = {0,0,0,0}, bvh = {0,0,0,0}, bvl = {0,0,0,0};
        if (aok) { avh = *(const uint4*)(Ah + aoff + k0); avl = *(const uint4*)(Al + aoff + k0); }
        if (bok) { bvh = *(const uint4*)(Bh + boff + k0); bvl = *(const uint4*)(Bl + boff + k0); }
        __syncthreads();
        *(uint4*)&AsH[lrow][lk] = avh; *(uint4*)&AsL[lrow][lk] = avl;
        *(uint4*)&BsH[lrow][lk] = bvh; *(uint4*)&BsL[lrow][lk] = bvl;
        __syncthreads();
        bf16x8 ah[2], al[2], bh[2], bl[2];
        ah[0] = *(const bf16x8*)&AsH[wr * 32 + r][g * 8];
        ah[1] = *(const bf16x8*)&AsH[wr * 32 + 16 + r][g * 8];
        al[0] = *(const bf16x8*)&AsL[wr * 32 + r][g * 8];
        al[1] = *(const bf16x8*)&AsL[wr * 32 + 16 + r][g * 8];
        bh[0] = *(const bf16x8*)&BsH[wc * 32 + r][g * 8];
        bh[1] = *(const bf16x8*)&BsH[wc * 32 + 16 + r][g * 8];
        bl[0] = *(const bf16x8*)&BsL[wc * 32 + r][g * 8];
        bl[1] = *(const bf16x8*)&BsL[wc * 32 + 16 + r][g * 8];
        for (int i = 0; i < 2; i++) for (int j = 0; j < 2; j++) {
            acc[i][j] = __builtin_amdgcn_mfma_f32_16x16x32_bf16(al[i], bh[j], acc[i][j], 0, 0, 0);
            acc[i][j] = __builtin_amdgcn_mfma_f32_16x16x32_bf16(ah[i], bl[j], acc[i][j], 0, 0, 0);
            acc[i][j] = __builtin_amdgcn_mfma_f32_16x16x32_bf16(ah[i], bh[j], acc[i][j], 0, 0, 0);
        }
    }
    for (int i = 0; i < 2; i++) for (int j = 0; j < 2; j++) {
        int col = n0 + wc * 32 + j * 16 + r;
        if (col >= N) continue;
        for (int e = 0; e < 4; e++) {
            int row = m0 + wr * 32 + i * 16 + g * 4 + e;
            if (row < M) C_[(size_t)row * N + col] = acc[i][j][e];
        }
    }
}

// ---------------- assemble qh/kh with RoPE ----------------
// global layout: qh/kh [(b*8+h)*2+sub][j2 in 0..24)[NS][2 floats]  (j2-interleaved for staging)
__global__ void assemble_qk(const float* __restrict__ qf, const float* __restrict__ kvf,
    const float* __restrict__ ckv, const float* __restrict__ freqs,
    float* __restrict__ qh, float* __restrict__ kh) {
    size_t idx = (size_t)blockIdx.x * 256 + threadIdx.x;
    const size_t total = (size_t)NB * H2N * 24 * NS;
    if (idx >= total) return;
    int s = (int)(idx % NS); size_t r = idx / NS;
    int j2 = (int)(r % 24); r /= 24;
    int sub = (int)(r & 1); r >>= 1;
    int h = (int)(r & 7); int b = (int)(r >> 3);
    int p = sub;
    size_t bs = (size_t)b * NS + s;
    float2 qv, kv2;
    if (j2 < 16) {
        const float* qp = qf + bs * 768 + h * 96 + p * 32 + j2 * 2;
        qv = make_float2(qp[0], qp[1]);
        const float* kp = kvf + bs * 1024 + h * 128 + p * 32 + j2 * 2;
        kv2 = make_float2(kp[0], kp[1]);
    } else {
        int i = j2 - 16;
        const float* qp = qf + bs * 768 + h * 96 + 64 + p * 16 + 2 * i;
        float xr = qp[0], xi = qp[1];
        const float* kp = ckv + bs * 288 + 256 + p * 16 + 2 * i;
        float yr = kp[0], yi = kp[1];
        if (s == 0) {
            qv = make_float2(xr, xi);
            kv2 = make_float2(yr, yi);
        } else {
            int pos = (s - 1) % SEQN;
            float c = freqs[pos * 16 + 2 * i], sn = freqs[pos * 16 + 2 * i + 1];
            qv = make_float2(xr * c - xi * sn, xr * sn + xi * c);
            kv2 = make_float2(yr * c - yi * sn, yr * sn + yi * c);
        }
    }
    *(float2*)(qh + idx * 2) = qv;
    *(float2*)(kh + idx * 2) = kv2;
}

// ---------------- attention pass A: per-row stats (m,z for both subs; signed sum g for sub0) ----
__global__ __launch_bounds__(256) void attn_pass_a(const float* __restrict__ qh,
    const float* __restrict__ kh, float* __restrict__ stats) {
    __shared__ float qs_[2][24][64][2];
    __shared__ float ks_[2][24][64][2];
    int tile = blockIdx.x, h = blockIdx.y, b = blockIdx.z;
    int qs0 = tile * 64;
    int tid = threadIdx.x;
    int qg = tid >> 4, kg = tid & 15;
    const size_t hb = (size_t)((b * 8 + h) * 2);

    // stage q tile (64 rows)
    {
        int qcount = NS - qs0; if (qcount > 64) qcount = 64;
        for (int i = 0; i < 12; i++) {
            int linear = i * 256 + tid;
            int key = linear & 63, flat = linear >> 6;
            int sub = flat / 24, j2 = flat % 24;
            float2 v = make_float2(0.f, 0.f);
            if (key < qcount)
                v = *(const float2*)(qh + (((hb + sub) * 24 + j2) * NS + qs0 + key) * 2);
            *(float2*)&qs_[sub][j2][key][0] = v;
        }
    }
    float m[2][4], z[2][4], gacc[4];
    for (int s2 = 0; s2 < 2; s2++) for (int i = 0; i < 4; i++) { m[s2][i] = NEG_INF; z[s2][i] = 0.f; }
    for (int i = 0; i < 4; i++) gacc[i] = 0.f;
    int qpos[4];
    for (int i = 0; i < 4; i++) { int q = qs0 + qg * 4 + i; qpos[i] = (q == 0) ? -1 : (q - 1) % SEQN; }
    int lo = qs0 < 1 ? 1 : qs0;
    int hi = qs0 + 63 < NS - 1 ? qs0 + 63 : NS - 1;
    int maxpos = ((lo - 1) / SEQN != (hi - 1) / SEQN) ? (SEQN - 1) : (hi - 1) % SEQN;

    for (int cblk = -1; cblk < 4; cblk++) {
        int base = (cblk < 0) ? 0 : 1 + cblk * SEQN;
        int len = (cblk < 0) ? 1 : maxpos + 1;
        for (int kb = 0; kb < len; kb += 64) {
            int kbase = base + kb;
            int count = (len - kb < 64) ? (len - kb) : 64;
            __syncthreads();
            for (int i = 0; i < 12; i++) {
                int linear = i * 256 + tid;
                int key = linear & 63, flat = linear >> 6;
                int sub = flat / 24, j2 = flat % 24;
                float2 v = make_float2(0.f, 0.f);
                if (key < count)
                    v = *(const float2*)(kh + (((hb + sub) * 24 + j2) * NS + kbase + key) * 2);
                *(float2*)&ks_[sub][j2][key][0] = v;
            }
            __syncthreads();
            float acc[2][4][4] = {};
            for (int sub = 0; sub < 2; sub++)
                for (int j2 = 0; j2 < 24; j2++) {
                    float2 kv4[4];
                    for (int kk = 0; kk < 4; kk++)
                        kv4[kk] = *(const float2*)&ks_[sub][j2][kg + 16 * kk][0];
                    for (int i = 0; i < 4; i++) {
                        float2 qv = *(const float2*)&qs_[sub][j2][qg * 4 + i][0];
                        for (int kk = 0; kk < 4; kk++)
                            acc[sub][i][kk] += qv.x * kv4[kk].x + qv.y * kv4[kk].y;
                    }
                }
            for (int i = 0; i < 4; i++) {
                bool um[4];
                for (int kk = 0; kk < 4; kk++) {
                    int klocal = kg + 16 * kk;
                    if (cblk < 0) um[kk] = (klocal == 0);
                    else { int kpos = kb + klocal; um[kk] = (klocal < count) && (kpos <= qpos[i]); }
                }
                for (int sub = 0; sub < 2; sub++) {
                    float aa[4], mx = NEG_INF;
                    for (int kk = 0; kk < 4; kk++) {
                        float a = acc[sub][i][kk] * SCAL;
                        aa[kk] = a;
                        float ab = um[kk] ? fabsf(a) : NEG_INF;
                        mx = fmaxf(mx, ab);
                    }
                    mx = fmaxf(mx, __shfl_xor(mx, 1));
                    mx = fmaxf(mx, __shfl_xor(mx, 2));
                    mx = fmaxf(mx, __shfl_xor(mx, 4));
                    mx = fmaxf(mx, __shfl_xor(mx, 8));
                    float mnew = fmaxf(m[sub][i], mx);
                    if (mnew == NEG_INF) continue;
                    float fac = (m[sub][i] == NEG_INF) ? 0.f : __expf(m[sub][i] - mnew);
                    float es = 0.f, gs = 0.f;
                    for (int kk = 0; kk < 4; kk++) {
                        if (!um[kk]) continue;
                        float e = __expf(fabsf(aa[kk]) - mnew);
                        es += e;
                        float sg = (aa[kk] > 0.f) ? 1.f : ((aa[kk] < 0.f) ? -1.f : 0.f);
                        gs += sg * e;
                    }
                    es += __shfl_xor(es, 1); gs += __shfl_xor(gs, 1);
                    es += __shfl_xor(es, 2); gs += __shfl_xor(gs, 2);
                    es += __shfl_xor(es, 4); gs += __shfl_xor(gs, 4);
                    es += __shfl_xor(es, 8); gs += __shfl_xor(gs, 8);
                    z[sub][i] = z[sub][i] * fac + es;
                    if (sub == 0) gacc[i] = gacc[i] * fac + gs;
                    m[sub][i] = mnew;
                }
            }
        }
    }
    if (kg == 0) {
        for (int i = 0; i < 4; i++) {
            int q = qs0 + qg * 4 + i;
            if (q < NS) {
                float* st = stats + ((size_t)((b * NH + h) * NS) + q) * 5;
                st[0] = m[0][i]; st[1] = z[0][i]; st[2] = m[1][i]; st[3] = z[1][i]; st[4] = gacc[i];
            }
        }
    }
}

// ---------------- attention pass B: combined weights + PV + head rmsnorm -> o_n (bf16) ------
__global__ __launch_bounds__(256) void attn_pass_b(const float* __restrict__ qh,
    const float* __restrict__ kh, const float* __restrict__ kvf, const float* __restrict__ stats,
    const float* __restrict__ lamp, const float* __restrict__ hw, unsigned short* __restrict__ o_n) {
    __shared__ float qs_[2][24][32][2];
    __shared__ float ks_[2][24][64][2];
    __shared__ float vs_[64][64];
    __shared__ float es_[32][65];
    __shared__ float st_[32][5];
    int tile = blockIdx.x, h = blockIdx.y, b = blockIdx.z;
    int qs0 = tile * 32;
    int tid = threadIdx.x;
    int qg = tid >> 5, kg = tid & 31;
    int oq = tid >> 3, ot = tid & 7;
    const size_t hb = (size_t)((b * 8 + h) * 2);
    float lam = lamp[0];
    {
        int qcount = NS - qs0; if (qcount > 32) qcount = 32;
        for (int i = 0; i < 6; i++) {
            int linear = i * 256 + tid;
            int qi = linear & 31, flat = linear >> 5;
            int sub = flat / 24, j2 = flat % 24;
            float2 v = make_float2(0.f, 0.f);
            if (qi < qcount)
                v = *(const float2*)(qh + (((hb + sub) * 24 + j2) * NS + qs0 + qi) * 2);
            *(float2*)&qs_[sub][j2][qi][0] = v;
        }
        if (tid < 32) {
            int q2 = qs0 + tid;
            float m0 = 0.f, m1 = 0.f, i0 = 0.f, l1 = 0.f, Gl = 0.f;
            if (q2 < NS) {
                const float* st = stats + ((size_t)((b * NH + h) * NS) + q2) * 5;
                m0 = st[0]; float z0 = st[1]; m1 = st[2]; float z1 = st[3]; float gg = st[4];
                i0 = 1.f / z0; l1 = lam / z1; Gl = lam * gg / (z0 * (float)NS);
            }
            st_[tid][0] = m0; st_[tid][1] = m1; st_[tid][2] = i0; st_[tid][3] = l1; st_[tid][4] = Gl;
        }
    }
    float oacc[8] = {};
    int qpos[4];
    for (int i = 0; i < 4; i++) { int q = qs0 + qg * 4 + i; qpos[i] = (q == 0) ? -1 : (q - 1) % SEQN; }
    int lo = qs0 < 1 ? 1 : qs0;
    int hi = qs0 + 31 < NS - 1 ? qs0 + 31 : NS - 1;
    int maxpos = ((lo - 1) / SEQN != (hi - 1) / SEQN) ? (SEQN - 1) : (hi - 1) % SEQN;

    for (int cblk = -1; cblk < 4; cblk++) {
        int base = (cblk < 0) ? 0 : 1 + cblk * SEQN;
        int len = (cblk < 0) ? 1 : maxpos + 1;
        for (int kb = 0; kb < len; kb += 64) {
            int kbase = base + kb;
            int count = (len - kb < 64) ? (len - kb) : 64;
            __syncthreads();
            for (int i = 0; i < 12; i++) {
                int linear = i * 256 + tid;
                int key = linear & 63, flat = linear >> 6;
                int sub = flat / 24, j2 = flat % 24;
                float2 v = make_float2(0.f, 0.f);
                if (key < count)
                    v = *(const float2*)(kh + (((hb + sub) * 24 + j2) * NS + kbase + key) * 2);
                *(float2*)&ks_[sub][j2][key][0] = v;
            }
            {
                int c4 = tid & 3, key2 = tid >> 2;
                for (int i = 0; i < 4; i++) {
                    int j4 = c4 + 4 * i;
                    f32x4 v = {0.f, 0.f, 0.f, 0.f};
                    if (key2 < count)
                        v = *(const f32x4*)(kvf + ((size_t)(b * NS + kbase + key2) * NH + h) * 128 + 64 + j4 * 4);
                    *(f32x4*)&vs_[key2][j4 * 4] = v;
                }
            }
            __syncthreads();
            float acc[2][4][2] = {};
            for (int sub = 0; sub < 2; sub++)
                for (int j2 = 0; j2 < 24; j2++) {
                    float2 k0 = *(const float2*)&ks_[sub][j2][kg][0];
                    float2 k1 = *(const float2*)&ks_[sub][j2][kg + 32][0];
                    for (int i = 0; i < 4; i++) {
                        float2 qv = *(const float2*)&qs_[sub][j2][qg * 4 + i][0];
                        acc[sub][i][0] += qv.x * k0.x + qv.y * k0.y;
                        acc[sub][i][1] += qv.x * k1.x + qv.y * k1.y;
                    }
                }
            for (int i = 0; i < 4; i++) {
                int qi = qg * 4 + i;
                float m0 = st_[qi][0], m1 = st_[qi][1], i0 = st_[qi][2], l1 = st_[qi][3], Gl = st_[qi][4];
                for (int kk = 0; kk < 2; kk++) {
                    int klocal = kg + 32 * kk;
                    bool um;
                    if (cblk < 0) um = (klocal == 0);
                    else { int kpos = kb + klocal; um = (klocal < count) && (kpos <= qpos[i]); }
                    float w = 0.f;
                    if (um) {
                        float a0 = acc[0][i][kk] * SCAL, a1 = acc[1][i][kk] * SCAL;
                        float e0 = __expf(fabsf(a0) - m0), e1 = __expf(fabsf(a1) - m1);
                        float s0 = (a0 > 0.f) ? 1.f : ((a0 < 0.f) ? -1.f : 0.f);
                        float s1 = (a1 > 0.f) ? 1.f : ((a1 < 0.f) ? -1.f : 0.f);
                        w = s0 * e0 * i0 - s1 * e1 * l1 + Gl;
                    }
                    es_[qi][klocal] = w;
                }
            }
            __syncthreads();
            for (int kk = 0; kk < 64; kk++) {
                float w = es_[oq][kk];
                f32x4 v0 = *(const f32x4*)&vs_[kk][ot * 8];
                f32x4 v1 = *(const f32x4*)&vs_[kk][ot * 8 + 4];
                oacc[0] += w * v0[0]; oacc[1] += w * v0[1]; oacc[2] += w * v0[2]; oacc[3] += w * v0[3];
                oacc[4] += w * v1[0]; oacc[5] += w * v1[1]; oacc[6] += w * v1[2]; oacc[7] += w * v1[3];
            }
        }
    }
    float ss = 0.f;
    for (int j = 0; j < 8; j++) ss += oacc[j] * oacc[j];
    ss += __shfl_xor(ss, 1); ss += __shfl_xor(ss, 2); ss += __shfl_xor(ss, 4);
    float rs = rsqrtf(ss / 64.f + 1e-5f);
    int q = qs0 + oq;
    if (q < NS) {
        for (int j = 0; j < 8; j++) {
            int d = ot * 8 + j;
            o_n[((size_t)(b * NS + q)) * 512 + h * 64 + d] = f2bf(oacc[j] * rs * hw[d]);
        }
    }
}

// ---------------- swiglu: uv(M x 3072) -> act bf16 (M x 1536) ----------------
__global__ void swiglu_k(const float* __restrict__ uv, unsigned short* __restrict__ act) {
    size_t idx = (size_t)blockIdx.x * 256 + threadIdx.x;
    if (idx >= (size_t)NM * DFF) return;
    size_t mrow = idx / DFF; int j = (int)(idx % DFF);
    float u = uv[mrow * (2 * DFF) + j];
    float gg = uv[mrow * (2 * DFF) + DFF + j];
    float sg = gg / (1.f + __expf(-gg));
    act[idx] = f2bf(u * sg);
}

// ---------------- host ----------------
extern "C" void kernel_launch(void* const* d_in, const int* in_sizes, int n_in,
                              void* d_out, int out_size, void* d_ws, size_t ws_size,
                              hipStream_t stream) {
    (void)in_sizes; (void)n_in; (void)out_size; (void)ws_size;
    const float* x    = (const float*)d_in[0];
    const float* freqs= (const float*)d_in[1];
    const float* Wkvd = (const float*)d_in[2];
    const float* Wqd  = (const float*)d_in[3];
    const float* Wkvu = (const float*)d_in[4];
    const float* Wqu  = (const float*)d_in[5];
    const float* kvnw = (const float*)d_in[6];
    const float* qnw  = (const float*)d_in[7];
    const float* Wo   = (const float*)d_in[8];
    const float* lq1  = (const float*)d_in[9];
    const float* lk1  = (const float*)d_in[10];
    const float* lq2  = (const float*)d_in[11];
    const float* lk2  = (const float*)d_in[12];
    const float* hnw  = (const float*)d_in[13];
    const float* n1w  = (const float*)d_in[14];
    const float* n2w  = (const float*)d_in[15];
    const float* Wffi = (const float*)d_in[16];
    const float* Wffo = (const float*)d_in[17];
    float* out = (float*)d_out;

    char* p = (char*)d_ws;
    auto alloc = [&](size_t nbytes) -> char* {
        char* r = p; p += (nbytes + 255) & ~(size_t)255; return r;
    };
    unsigned short* wkvd_h = (unsigned short*)alloc((size_t)512 * 288 * 2);
    unsigned short* wkvd_l = (unsigned short*)alloc((size_t)512 * 288 * 2);
    unsigned short* wqd_h  = (unsigned short*)alloc((size_t)512 * 384 * 2);
    unsigned short* wqd_l  = (unsigned short*)alloc((size_t)512 * 384 * 2);
    unsigned short* wkvu_h = (unsigned short*)alloc((size_t)256 * 1024 * 2);
    unsigned short* wkvu_l = (unsigned short*)alloc((size_t)256 * 1024 * 2);
    unsigned short* wqu_h  = (unsigned short*)alloc((size_t)384 * 768 * 2);
    unsigned short* wqu_l  = (unsigned short*)alloc((size_t)384 * 768 * 2);
    unsigned short* wo_h   = (unsigned short*)alloc((size_t)512 * 512 * 2);
    unsigned short* wffi_h = (unsigned short*)alloc((size_t)512 * 3072 * 2);
    unsigned short* wffo_h = (unsigned short*)alloc((size_t)1536 * 512 * 2);
    unsigned short* h_hi   = (unsigned short*)alloc((size_t)NM * 512 * 2);
    unsigned short* h_lo   = (unsigned short*)alloc((size_t)NM * 512 * 2);
    float* ckv = (float*)alloc((size_t)NM * 288 * 4);
    float* qd  = (float*)alloc((size_t)NM * 384 * 4);
    unsigned short* ckvn_h = (unsigned short*)alloc((size_t)NM * 256 * 2);
    unsigned short* ckvn_l = (unsigned short*)alloc((size_t)NM * 256 * 2);
    unsigned short* qdn_h  = (unsigned short*)alloc((size_t)NM * 384 * 2);
    unsigned short* qdn_l  = (unsigned short*)alloc((size_t)NM * 384 * 2);
    // big union region: {kv, qf, qh, kh} phase1  ->  {uv} phase2
    size_t qhf = (size_t)NB * H2N * 24 * NS * 2; // floats in qh (= kh)
    size_t region_f = (size_t)NM * 1024 + (size_t)NM * 768 + 2 * qhf;
    char* region = alloc(region_f * 4);
    float* kvf = (float*)region;
    float* qff = kvf + (size_t)NM * 1024;
    float* qh  = qff + (size_t)NM * 768;
    float* kh  = qh + qhf;
    float* uv  = (float*)region;
    float* stats = (float*)alloc((size_t)NB * NH * NS * 5 * 4);
    float* lamv  = (float*)alloc(256);
    unsigned short* o_n = (unsigned short*)alloc((size_t)NM * 512 * 2);
    float* x2 = (float*)alloc((size_t)NM * 512 * 4);
    unsigned short* h2 = (unsigned short*)alloc((size_t)NM * 512 * 2);
    unsigned short* act = (unsigned short*)alloc((size_t)NM * 1536 * 2);

    auto T = [&](const float* w, unsigned short* hi_, unsigned short* lo_, int K, int N) {
        dim3 g((K + 31) / 32, (N + 31) / 32);
        transpose_split<<<g, 256, 0, stream>>>(w, hi_, lo_, K, N);
    };
    T(Wkvd, wkvd_h, wkvd_l, 512, 288);
    T(Wqd,  wqd_h,  wqd_l,  512, 384);
    T(Wkvu, wkvu_h, wkvu_l, 256, 1024);
    T(Wqu,  wqu_h,  wqu_l,  384, 768);
    T(Wo,   wo_h,   nullptr, 512, 512);
    T(Wffi, wffi_h, nullptr, 512, 3072);
    T(Wffo, wffo_h, nullptr, 1536, 512);
    lam_kernel<<<1, 64, 0, stream>>>(lq1, lk1, lq2, lk2, lamv);

    rmsnorm_k<<<NM, 256, 0, stream>>>(x, n1w, h_hi, h_lo, 512, 512, EPS1);

    const int GX = (NM + 63) / 64;
    gemm_x3<<<dim3(GX, (288 + 63) / 64), 256, 0, stream>>>(h_hi, h_lo, wkvd_h, wkvd_l, ckv, NM, 288, 512);
    gemm_x3<<<dim3(GX, (384 + 63) / 64), 256, 0, stream>>>(h_hi, h_lo, wqd_h, wqd_l, qd, NM, 384, 512);

    rmsnorm_k<<<NM, 256, 0, stream>>>(ckv, kvnw, ckvn_h, ckvn_l, 288, 256, EPS1);
    rmsnorm_k<<<NM, 256, 0, stream>>>(qd, qnw, qdn_h, qdn_l, 384, 384, EPS1);

    gemm_x3<<<dim3(GX, 1024 / 64), 256, 0, stream>>>(ckvn_h, ckvn_l, wkvu_h, wkvu_l, kvf, NM, 1024, 256);
    gemm_x3<<<dim3(GX, 768 / 64), 256, 0, stream>>>(qdn_h, qdn_l, wqu_h, wqu_l, qff, NM, 768, 384);

    {
        size_t total = (size_t)NB * H2N * 24 * NS;
        assemble_qk<<<dim3((unsigned)((total + 255) / 256)), 256, 0, stream>>>(qff, kvf, ckv, freqs, qh, kh);
    }
    attn_pass_a<<<dim3((NS + 63) / 64, NH, NB), 256, 0, stream>>>(qh, kh, stats);
    attn_pass_b<<<dim3((NS + 31) / 32, NH, NB), 256, 0, stream>>>(qh, kh, kvf, stats, lamv, hnw, o_n);

    gemm_single<<<dim3(GX, 512 / 64), 256, 0, stream>>>(o_n, wo_h, x2, x, NM, 512, 512);
    rmsnorm_k<<<NM, 256, 0, stream>>>(x2, n2w, h2, nullptr, 512, 512, EPS1);
    gemm_single<<<dim3(GX, 3072 / 64), 256, 0, stream>>>(h2, wffi_h, uv, nullptr, NM, 3072, 512);
    {
        size_t total = (size_t)NM * DFF;
        swiglu_k<<<dim3((unsigned)((total + 255) / 256)), 256, 0, stream>>>(uv, act);
    }
    gemm_single<<<dim3(GX, 512 / 64), 256, 0, stream>>>(act, wffo_h, out, x2, NM, 512, 1536);
}

// Round 4
// 405.361 us; speedup vs baseline: 12.8535x; 12.8535x over previous
//
#include <hip/hip_runtime.h>

#define NB 2
#define SEQN 384
#define NS 1537
#define NS_PAD 1600
#define NH 8
#define H2N 16
#define NM (NB*NS)
#define DFF 1536
#define EPS1 1.1920929e-07f
#define SCAL (1.0f/48.0f)

typedef __bf16 bf16x8 __attribute__((ext_vector_type(8)));
typedef _Float16 f16x8 __attribute__((ext_vector_type(8)));
typedef float f32x4 __attribute__((ext_vector_type(4)));

__device__ __forceinline__ unsigned short f2bf(float f) {
    unsigned int u = __builtin_bit_cast(unsigned int, f);
    u += 0x7FFFu + ((u >> 16) & 1u);
    return (unsigned short)(u >> 16);
}
__device__ __forceinline__ float bf2f(unsigned short h) {
    unsigned int u = ((unsigned int)h) << 16;
    return __builtin_bit_cast(float, u);
}

// ---------------- transpose weights (KxN f32 -> NxK bf16 hi[/lo]) ----------------
__global__ void transpose_split(const float* __restrict__ w, unsigned short* __restrict__ hi,
                                unsigned short* __restrict__ lo, int K, int N) {
    __shared__ float tile[32][33];
    int k0 = blockIdx.x * 32, n0 = blockIdx.y * 32;
    int tx = threadIdx.x & 31, ty4 = (threadIdx.x >> 5) * 4;
    for (int i = 0; i < 4; i++) {
        int k = k0 + ty4 + i, n = n0 + tx;
        tile[ty4 + i][tx] = (k < K && n < N) ? w[(size_t)k * N + n] : 0.f;
    }
    __syncthreads();
    for (int i = 0; i < 4; i++) {
        int n = n0 + ty4 + i, k = k0 + tx;
        if (n < N && k < K) {
            float v = tile[tx][ty4 + i];
            unsigned short hb = f2bf(v);
            size_t o = (size_t)n * K + k;
            hi[o] = hb;
            if (lo) lo[o] = f2bf(v - bf2f(hb));
        }
    }
}

// ---------------- lambda scalar ----------------
__global__ void lam_kernel(const float* q1, const float* k1, const float* q2, const float* k2,
                           float* out) {
    int t = threadIdx.x;
    float p1 = 0.f, p2 = 0.f;
    if (t < 32) { p1 = q1[t] * k1[t]; p2 = q2[t] * k2[t]; }
    for (int o = 1; o < 32; o <<= 1) { p1 += __shfl_xor(p1, o); p2 += __shfl_xor(p2, o); }
    if (t == 0) out[0] = expf(p1) - expf(p2) + 0.2f;
}

// ---------------- rmsnorm (f32 in, bf16 hi[/lo] out) ----------------
__global__ __launch_bounds__(256) void rmsnorm_k(const float* __restrict__ in,
    const float* __restrict__ w, unsigned short* __restrict__ hi, unsigned short* __restrict__ lo,
    int in_stride, int C, float eps) {
    int row = blockIdx.x;
    const float* x = in + (size_t)row * in_stride;
    float ss = 0.f;
    for (int j = threadIdx.x; j < C; j += 256) { float v = x[j]; ss += v * v; }
    for (int o = 1; o < 64; o <<= 1) ss += __shfl_xor(ss, o);
    __shared__ float red[4];
    if ((threadIdx.x & 63) == 0) red[threadIdx.x >> 6] = ss;
    __syncthreads();
    ss = red[0] + red[1] + red[2] + red[3];
    float rs = rsqrtf(ss / (float)C + eps);
    for (int j = threadIdx.x; j < C; j += 256) {
        float y = x[j] * rs * w[j];
        unsigned short hb = f2bf(y);
        hi[(size_t)row * C + j] = hb;
        if (lo) lo[(size_t)row * C + j] = f2bf(y - bf2f(hb));
    }
}

// ---------------- single-bf16 GEMM: C(MxN) = A(MxK) * Bt(NxK)^T [+res] ----------------
__global__ __launch_bounds__(256) void gemm_single(const unsigned short* __restrict__ A,
    const unsigned short* __restrict__ Bt, float* __restrict__ C_, const float* __restrict__ res,
    int M, int N, int K) {
    __shared__ unsigned short As[64][32];
    __shared__ unsigned short Bs[64][32];
    int m0 = blockIdx.x * 64, n0 = blockIdx.y * 64;
    int tid = threadIdx.x;
    int lane = tid & 63, wid = tid >> 6;
    int wr = wid >> 1, wc = wid & 1;
    int r = lane & 15, g = lane >> 4;
    int lrow = tid >> 2, lk = (tid & 3) * 8;
    f32x4 acc[2][2] = {};
    int arow = m0 + lrow, brow = n0 + lrow;
    bool aok = arow < M, bok = brow < N;
    size_t aoff = (size_t)arow * K + lk, boff = (size_t)brow * K + lk;
    for (int k0 = 0; k0 < K; k0 += 32) {
        uint4 av = {0,0,0,0}, bv = {0,0,0,0};
        if (aok) av = *(const uint4*)(A + aoff + k0);
        if (bok) bv = *(const uint4*)(Bt + boff + k0);
        __syncthreads();
        *(uint4*)&As[lrow][lk] = av;
        *(uint4*)&Bs[lrow][lk] = bv;
        __syncthreads();
        bf16x8 a0 = *(const bf16x8*)&As[wr * 32 + r][g * 8];
        bf16x8 a1 = *(const bf16x8*)&As[wr * 32 + 16 + r][g * 8];
        bf16x8 b0 = *(const bf16x8*)&Bs[wc * 32 + r][g * 8];
        bf16x8 b1 = *(const bf16x8*)&Bs[wc * 32 + 16 + r][g * 8];
        acc[0][0] = __builtin_amdgcn_mfma_f32_16x16x32_bf16(a0, b0, acc[0][0], 0, 0, 0);
        acc[0][1] = __builtin_amdgcn_mfma_f32_16x16x32_bf16(a0, b1, acc[0][1], 0, 0, 0);
        acc[1][0] = __builtin_amdgcn_mfma_f32_16x16x32_bf16(a1, b0, acc[1][0], 0, 0, 0);
        acc[1][1] = __builtin_amdgcn_mfma_f32_16x16x32_bf16(a1, b1, acc[1][1], 0, 0, 0);
    }
    for (int i = 0; i < 2; i++) for (int j = 0; j < 2; j++) {
        int col = n0 + wc * 32 + j * 16 + r;
        if (col >= N) continue;
        for (int e = 0; e < 4; e++) {
            int row = m0 + wr * 32 + i * 16 + g * 4 + e;
            if (row >= M) continue;
            float v = acc[i][j][e];
            if (res) v += res[(size_t)row * N + col];
            C_[(size_t)row * N + col] = v;
        }
    }
}

// ---------------- split-bf16 (hi+lo, 3xMFMA) GEMM: near-fp32 precision ----------------
__global__ __launch_bounds__(256) void gemm_x3(const unsigned short* __restrict__ Ah,
    const unsigned short* __restrict__ Al, const unsigned short* __restrict__ Bh,
    const unsigned short* __restrict__ Bl, float* __restrict__ C_, int M, int N, int K) {
    __shared__ unsigned short AsH[64][32], AsL[64][32], BsH[64][32], BsL[64][32];
    int m0 = blockIdx.x * 64, n0 = blockIdx.y * 64;
    int tid = threadIdx.x;
    int lane = tid & 63, wid = tid >> 6;
    int wr = wid >> 1, wc = wid & 1;
    int r = lane & 15, g = lane >> 4;
    int lrow = tid >> 2, lk = (tid & 3) * 8;
    f32x4 acc[2][2] = {};
    int arow = m0 + lrow, brow = n0 + lrow;
    bool aok = arow < M, bok = brow < N;
    size_t aoff = (size_t)arow * K + lk, boff = (size_t)brow * K + lk;
    for (int k0 = 0; k0 < K; k0 += 32) {
        uint4 avh = {0,0,0,0}, avl = {0,0,0,0}, bvh = {0,0,0,0}, bvl = {0,0,0,0};
        if (aok) { avh = *(const uint4*)(Ah + aoff + k0); avl = *(const uint4*)(Al + aoff + k0); }
        if (bok) { bvh = *(const uint4*)(Bh + boff + k0); bvl = *(const uint4*)(Bl + boff + k0); }
        __syncthreads();
        *(uint4*)&AsH[lrow][lk] = avh; *(uint4*)&AsL[lrow][lk] = avl;
        *(uint4*)&BsH[lrow][lk] = bvh; *(uint4*)&BsL[lrow][lk] = bvl;
        __syncthreads();
        bf16x8 ah[2], al[2], bh[2], bl[2];
        ah[0] = *(const bf16x8*)&AsH[wr * 32 + r][g * 8];
        ah[1] = *(const bf16x8*)&AsH[wr * 32 + 16 + r][g * 8];
        al[0] = *(const bf16x8*)&AsL[wr * 32 + r][g * 8];
        al[1] = *(const bf16x8*)&AsL[wr * 32 + 16 + r][g * 8];
        bh[0] = *(const bf16x8*)&BsH[wc * 32 + r][g * 8];
        bh[1] = *(const bf16x8*)&BsH[wc * 32 + 16 + r][g * 8];
        bl[0] = *(const bf16x8*)&BsL[wc * 32 + r][g * 8];
        bl[1] = *(const bf16x8*)&BsL[wc * 32 + 16 + r][g * 8];
        for (int i = 0; i < 2; i++) for (int j = 0; j < 2; j++) {
            acc[i][j] = __builtin_amdgcn_mfma_f32_16x16x32_bf16(al[i], bh[j], acc[i][j], 0, 0, 0);
            acc[i][j] = __builtin_amdgcn_mfma_f32_16x16x32_bf16(ah[i], bl[j], acc[i][j], 0, 0, 0);
            acc[i][j] = __builtin_amdgcn_mfma_f32_16x16x32_bf16(ah[i], bh[j], acc[i][j], 0, 0, 0);
        }
    }
    for (int i = 0; i < 2; i++) for (int j = 0; j < 2; j++) {
        int col = n0 + wc * 32 + j * 16 + r;
        if (col >= N) continue;
        for (int e = 0; e < 4; e++) {
            int row = m0 + wr * 32 + i * 16 + g * 4 + e;
            if (row < M) C_[(size_t)row * N + col] = acc[i][j][e];
        }
    }
}

// ---------------- assemble q/k heads (f16 hi/lo, RoPE applied, padded 48->64) ------
// layout: each of qgh/qgl/kgh/kgl : [ (b*8+h)*2+sub ][ NS_PAD ][ 64 ] f16
__global__ void assemble2(const float* __restrict__ qf_, const float* __restrict__ kvf,
    const float* __restrict__ ckv, const float* __restrict__ freqs,
    _Float16* __restrict__ qgh, _Float16* __restrict__ qgl,
    _Float16* __restrict__ kgh, _Float16* __restrict__ kgl) {
    size_t idx = (size_t)blockIdx.x * 256 + threadIdx.x;
    const size_t total = (size_t)NB * H2N * NS_PAD * 32;
    if (idx >= total) return;
    int j2 = (int)(idx & 31);
    size_t t = idx >> 5;
    int s = (int)(t % NS_PAD); size_t r = t / NS_PAD;
    int sub = (int)(r & 1); r >>= 1;
    int h = (int)(r & 7); int b = (int)(r >> 3);
    float2 qv = make_float2(0.f, 0.f), kv2 = make_float2(0.f, 0.f);
    if (s < NS && j2 < 24) {
        size_t bs = (size_t)b * NS + s;
        if (j2 < 16) {
            const float* qp = qf_ + bs * 768 + h * 96 + sub * 32 + j2 * 2;
            qv = make_float2(qp[0], qp[1]);
            const float* kp = kvf + bs * 1024 + h * 128 + sub * 32 + j2 * 2;
            kv2 = make_float2(kp[0], kp[1]);
        } else {
            int i = j2 - 16;
            const float* qp = qf_ + bs * 768 + h * 96 + 64 + sub * 16 + 2 * i;
            float xr = qp[0], xi = qp[1];
            const float* kp = ckv + bs * 288 + 256 + sub * 16 + 2 * i;
            float yr = kp[0], yi = kp[1];
            if (s == 0) {
                qv = make_float2(xr, xi);
                kv2 = make_float2(yr, yi);
            } else {
                int pos = (s - 1) % SEQN;
                float c = freqs[pos * 16 + 2 * i], sn = freqs[pos * 16 + 2 * i + 1];
                qv = make_float2(xr * c - xi * sn, xr * sn + xi * c);
                kv2 = make_float2(yr * c - yi * sn, yr * sn + yi * c);
            }
        }
    }
    _Float16 qx = (_Float16)qv.x, qy = (_Float16)qv.y;
    _Float16 kx = (_Float16)kv2.x, ky = (_Float16)kv2.y;
    qgh[idx * 2] = qx; qgh[idx * 2 + 1] = qy;
    kgh[idx * 2] = kx; kgh[idx * 2 + 1] = ky;
    qgl[idx * 2] = (_Float16)(qv.x - (float)qx); qgl[idx * 2 + 1] = (_Float16)(qv.y - (float)qy);
    kgl[idx * 2] = (_Float16)(kv2.x - (float)kx); kgl[idx * 2 + 1] = (_Float16)(kv2.y - (float)ky);
}

// ---------------- V transpose: kvf -> vt [ (b*8+h)*64 + d ][ NS_PAD ] f16 ----------------
__global__ __launch_bounds__(256) void vtrans(const float* __restrict__ kvf,
                                              _Float16* __restrict__ vt) {
    __shared__ float tile[64][65];
    int k0 = blockIdx.x * 64;
    int b = blockIdx.y >> 3, h = blockIdx.y & 7;
    int tid = threadIdx.x;
    int row = tid >> 2, cq = (tid & 3) * 16;
    for (int i = 0; i < 16; i++) {
        int key = k0 + row;
        tile[row][cq + i] = (key < NS)
            ? kvf[((size_t)(b * NS + key)) * 1024 + h * 128 + 64 + cq + i] : 0.f;
    }
    __syncthreads();
    int d = tid >> 2, kq = (tid & 3) * 16;
    for (int i = 0; i < 16; i++)
        vt[((size_t)((b * 8 + h) * 64 + d)) * NS_PAD + k0 + kq + i] = (_Float16)tile[kq + i][d];
}

// ---------------- P4: prefix sums of (sum over 4 chunks of v) per position ----------------
__global__ void p4sum(const float* __restrict__ kvf, float* __restrict__ P4) {
    int d = threadIdx.x;           // 0..63
    int b = blockIdx.x >> 3, h = blockIdx.x & 7;
    float acc = 0.f;
    for (int p = 0; p < SEQN; p++) {
        for (int c = 0; c < 4; c++)
            acc += kvf[((size_t)(b * NS + 1 + c * SEQN + p)) * 1024 + h * 128 + 64 + d];
        P4[((size_t)blockIdx.x * SEQN + p) * 64 + d] = acc;
    }
}

// ---------------- flash differential attention + head rmsnorm -> o_n (bf16) --------------
__global__ __launch_bounds__(256) void flash_attn(
    const _Float16* __restrict__ qgh, const _Float16* __restrict__ qgl,
    const _Float16* __restrict__ kgh, const _Float16* __restrict__ kgl,
    const _Float16* __restrict__ vt,
    const float* __restrict__ kvf, const float* __restrict__ P4,
    const float* __restrict__ lamp, const float* __restrict__ hw,
    unsigned short* __restrict__ o_n) {
    __shared__ _Float16 Ksh[2][64][72];
    __shared__ _Float16 Ksl[2][64][72];
    __shared__ _Float16 Vt[64][72];
    __shared__ _Float16 Pl[4][16][72];
    const int tile = blockIdx.x, h = blockIdx.y, b = blockIdx.z;
    const int qs0 = tile * 64;
    const int tid = threadIdx.x;
    const int wave = tid >> 6, lane = tid & 63;
    const int r = lane & 15, g = lane >> 4;
    const int qrow = qs0 + wave * 16;
    const size_t sh0 = (size_t)((b * 8 + h) * 2);

    // Q fragments (A-operand), hi+lo, held in registers for the whole kernel
    f16x8 qfh[2][2], qfl[2][2];
    #pragma unroll
    for (int sub = 0; sub < 2; sub++)
        #pragma unroll
        for (int ks = 0; ks < 2; ks++) {
            size_t off = ((sh0 + sub) * NS_PAD + qrow + r) * 64 + ks * 32 + g * 8;
            qfh[sub][ks] = *(const f16x8*)(qgh + off);
            qfl[sub][ks] = *(const f16x8*)(qgl + off);
        }

    float m0[4], z0[4], g0a[4], m1[4], z1[4];
    f32x4 O0[4], O1[4];
    #pragma unroll
    for (int e = 0; e < 4; e++) {
        m0[e] = -3e38f; z0[e] = 0.f; g0a[e] = 0.f; m1[e] = -3e38f; z1[e] = 0.f;
        O0[e] = (f32x4){0.f,0.f,0.f,0.f}; O1[e] = (f32x4){0.f,0.f,0.f,0.f};
    }
    int qpos[4];
    #pragma unroll
    for (int e = 0; e < 4; e++) {
        int q = qrow + g * 4 + e;
        qpos[e] = (q == 0) ? -1 : (q - 1) % SEQN;
    }
    int lo = qs0 < 1 ? 1 : qs0;
    int hi = qs0 + 63 < NS - 1 ? qs0 + 63 : NS - 1;
    int maxpos = ((lo - 1) / SEQN != (hi - 1) / SEQN) ? (SEQN - 1) : (hi - 1) % SEQN;

    for (int c = 0; c < 4; c++) {
        int nb = (c == 0) ? ((maxpos + 2 + 63) >> 6) : ((maxpos + 1 + 63) >> 6);
        int kstart = (c == 0) ? 0 : (c * SEQN + 1);
        int cbase = c * SEQN + 1;   // key index of chunk-c position 0
        for (int j = 0; j < nb; j++) {
            int kbase = kstart + j * 64;
            __syncthreads();
            // stage K hi+lo (2 subs) : each 64x64 f16 contiguous in global
            #pragma unroll
            for (int i = 0; i < 4; i++) {
                int chunk = i * 256 + tid;          // 0..1023
                int arr = chunk >> 9;
                int cc = chunk & 511;
                int row = cc >> 3, c8 = (cc & 7) * 8;
                size_t goff = ((sh0 + arr) * NS_PAD + kbase + row) * 64 + c8;
                *(uint4*)&Ksh[arr][row][c8] = *(const uint4*)(kgh + goff);
                *(uint4*)&Ksl[arr][row][c8] = *(const uint4*)(kgl + goff);
            }
            // stage V^T : 64 d-rows x 64 keys
            #pragma unroll
            for (int i = 0; i < 2; i++) {
                int cc = i * 256 + tid;             // 0..511
                int d = cc >> 3, c8 = (cc & 7) * 8;
                *(uint4*)&Vt[d][c8] =
                    *(const uint4*)(vt + ((size_t)((b * 8 + h) * 64 + d)) * NS_PAD + kbase + c8);
            }
            __syncthreads();

            // V B-fragments (shared by both chains)
            f16x8 bv[4][2];
            #pragma unroll
            for (int dt = 0; dt < 4; dt++)
                #pragma unroll
                for (int ks = 0; ks < 2; ks++)
                    bv[dt][ks] = *(const f16x8*)&Vt[dt * 16 + r][ks * 32 + g * 8];

            // key indices / chunk-relative positions for this lane's 4 score columns
            int kidx[4], rel[4];
            #pragma unroll
            for (int t4 = 0; t4 < 4; t4++) {
                int kk2 = kbase + t4 * 16 + r;
                kidx[t4] = kk2;
                rel[t4] = kk2 - cbase;   // in [0,SEQN) iff key belongs to chunk c
            }

            #pragma unroll
            for (int sub = 0; sub < 2; sub++) {
                // QK^T for this sub : split-f16 (qh*kh + ql*kh + qh*kl) ~ fp32 accurate
                f32x4 acc[4];
                #pragma unroll
                for (int t4 = 0; t4 < 4; t4++) acc[t4] = (f32x4){0.f,0.f,0.f,0.f};
                #pragma unroll
                for (int t4 = 0; t4 < 4; t4++)
                    #pragma unroll
                    for (int ks = 0; ks < 2; ks++) {
                        f16x8 bkh = *(const f16x8*)&Ksh[sub][t4 * 16 + r][ks * 32 + g * 8];
                        f16x8 bkl = *(const f16x8*)&Ksl[sub][t4 * 16 + r][ks * 32 + g * 8];
                        acc[t4] = __builtin_amdgcn_mfma_f32_16x16x32_f16(qfl[sub][ks], bkh, acc[t4], 0, 0, 0);
                        acc[t4] = __builtin_amdgcn_mfma_f32_16x16x32_f16(qfh[sub][ks], bkl, acc[t4], 0, 0, 0);
                        acc[t4] = __builtin_amdgcn_mfma_f32_16x16x32_f16(qfh[sub][ks], bkh, acc[t4], 0, 0, 0);
                    }
                // online stats + P values
                float pv[4][4];
                float fac[4];
                #pragma unroll
                for (int e = 0; e < 4; e++) {
                    float a[4]; bool um[4];
                    float mx = -3e38f;
                    #pragma unroll
                    for (int t4 = 0; t4 < 4; t4++) {
                        um[t4] = (kidx[t4] == 0) ||
                                 ((unsigned)rel[t4] < (unsigned)SEQN && rel[t4] <= qpos[e]);
                        a[t4] = acc[t4][e] * SCAL;
                        mx = fmaxf(mx, um[t4] ? fabsf(a[t4]) : -3e38f);
                    }
                    mx = fmaxf(mx, __shfl_xor(mx, 1));
                    mx = fmaxf(mx, __shfl_xor(mx, 2));
                    mx = fmaxf(mx, __shfl_xor(mx, 4));
                    mx = fmaxf(mx, __shfl_xor(mx, 8));
                    float mold = (sub == 0) ? m0[e] : m1[e];
                    float mnew = fmaxf(mold, mx);
                    float es = 0.f, gs = 0.f;
                    #pragma unroll
                    for (int t4 = 0; t4 < 4; t4++) {
                        float ev = um[t4] ? __expf(fabsf(a[t4]) - mnew) : 0.f;
                        float sg = (a[t4] > 0.f) ? 1.f : ((a[t4] < 0.f) ? -1.f : 0.f);
                        pv[e][t4] = sg * ev;
                        es += ev; gs += sg * ev;
                    }
                    es += __shfl_xor(es, 1); es += __shfl_xor(es, 2);
                    es += __shfl_xor(es, 4); es += __shfl_xor(es, 8);
                    float f = __expf(mold - mnew);
                    fac[e] = f;
                    if (sub == 0) {
                        gs += __shfl_xor(gs, 1); gs += __shfl_xor(gs, 2);
                        gs += __shfl_xor(gs, 4); gs += __shfl_xor(gs, 8);
                        z0[e] = z0[e] * f + es; g0a[e] = g0a[e] * f + gs; m0[e] = mnew;
                    } else {
                        z1[e] = z1[e] * f + es; m1[e] = mnew;
                    }
                }
                // rescale O, write P, PV
                #pragma unroll
                for (int dt = 0; dt < 4; dt++)
                    #pragma unroll
                    for (int e = 0; e < 4; e++) {
                        if (sub == 0) O0[dt][e] *= fac[e]; else O1[dt][e] *= fac[e];
                    }
                #pragma unroll
                for (int e = 0; e < 4; e++)
                    #pragma unroll
                    for (int t4 = 0; t4 < 4; t4++)
                        Pl[wave][g * 4 + e][t4 * 16 + r] = (_Float16)pv[e][t4];
                __builtin_amdgcn_wave_barrier();
                f16x8 pa0 = *(const f16x8*)&Pl[wave][r][g * 8];
                f16x8 pa1 = *(const f16x8*)&Pl[wave][r][32 + g * 8];
                #pragma unroll
                for (int dt = 0; dt < 4; dt++) {
                    if (sub == 0) {
                        O0[dt] = __builtin_amdgcn_mfma_f32_16x16x32_f16(pa0, bv[dt][0], O0[dt], 0, 0, 0);
                        O0[dt] = __builtin_amdgcn_mfma_f32_16x16x32_f16(pa1, bv[dt][1], O0[dt], 0, 0, 0);
                    } else {
                        O1[dt] = __builtin_amdgcn_mfma_f32_16x16x32_f16(pa0, bv[dt][0], O1[dt], 0, 0, 0);
                        O1[dt] = __builtin_amdgcn_mfma_f32_16x16x32_f16(pa1, bv[dt][1], O1[dt], 0, 0, 0);
                    }
                }
            }
        }
    }

    // epilogue: combine chains + G-term, head rmsnorm, store
    float lam = lamp[0];
    float v0d[4], hwd[4];
    #pragma unroll
    for (int dt = 0; dt < 4; dt++) {
        int d = dt * 16 + r;
        v0d[dt] = kvf[((size_t)(b * NS)) * 1024 + h * 128 + 64 + d];
        hwd[dt] = hw[d];
    }
    #pragma unroll
    for (int e = 0; e < 4; e++) {
        int q = qrow + g * 4 + e;
        if (q >= NS) continue;
        float iz0 = 1.f / z0[e];
        float l1 = lam / z1[e];
        float Gl = lam * g0a[e] * iz0 * (1.f / (float)NS);
        float of[4]; float ss = 0.f;
        #pragma unroll
        for (int dt = 0; dt < 4; dt++) {
            float vs = v0d[dt];
            if (qpos[e] >= 0)
                vs += P4[((size_t)(b * 8 + h) * SEQN + qpos[e]) * 64 + dt * 16 + r];
            float o = O0[dt][e] * iz0 - O1[dt][e] * l1 + Gl * vs;
            of[dt] = o; ss += o * o;
        }
        ss += __shfl_xor(ss, 1); ss += __shfl_xor(ss, 2);
        ss += __shfl_xor(ss, 4); ss += __shfl_xor(ss, 8);
        float rs = rsqrtf(ss / 64.f + 1e-5f);
        #pragma unroll
        for (int dt = 0; dt < 4; dt++)
            o_n[((size_t)(b * NS + q)) * 512 + h * 64 + dt * 16 + r] = f2bf(of[dt] * rs * hwd[dt]);
    }
}

// ---------------- swiglu: uv(M x 3072) -> act bf16 (M x 1536) ----------------
__global__ void swiglu_k(const float* __restrict__ uv, unsigned short* __restrict__ act) {
    size_t idx = (size_t)blockIdx.x * 256 + threadIdx.x;
    if (idx >= (size_t)NM * DFF) return;
    size_t mrow = idx / DFF; int j = (int)(idx % DFF);
    float u = uv[mrow * (2 * DFF) + j];
    float gg = uv[mrow * (2 * DFF) + DFF + j];
    float sg = gg / (1.f + __expf(-gg));
    act[idx] = f2bf(u * sg);
}

// ---------------- host ----------------
extern "C" void kernel_launch(void* const* d_in, const int* in_sizes, int n_in,
                              void* d_out, int out_size, void* d_ws, size_t ws_size,
                              hipStream_t stream) {
    (void)in_sizes; (void)n_in; (void)out_size; (void)ws_size;
    const float* x    = (const float*)d_in[0];
    const float* freqs= (const float*)d_in[1];
    const float* Wkvd = (const float*)d_in[2];
    const float* Wqd  = (const float*)d_in[3];
    const float* Wkvu = (const float*)d_in[4];
    const float* Wqu  = (const float*)d_in[5];
    const float* kvnw = (const float*)d_in[6];
    const float* qnw  = (const float*)d_in[7];
    const float* Wo   = (const float*)d_in[8];
    const float* lq1  = (const float*)d_in[9];
    const float* lk1  = (const float*)d_in[10];
    const float* lq2  = (const float*)d_in[11];
    const float* lk2  = (const float*)d_in[12];
    const float* hnw  = (const float*)d_in[13];
    const float* n1w  = (const float*)d_in[14];
    const float* n2w  = (const float*)d_in[15];
    const float* Wffi = (const float*)d_in[16];
    const float* Wffo = (const float*)d_in[17];
    float* out = (float*)d_out;

    char* p = (char*)d_ws;
    auto alloc = [&](size_t nbytes) -> char* {
        char* r = p; p += (nbytes + 255) & ~(size_t)255; return r;
    };
    // weights
    unsigned short* wkvd_h = (unsigned short*)alloc((size_t)512 * 288 * 2);
    unsigned short* wkvd_l = (unsigned short*)alloc((size_t)512 * 288 * 2);
    unsigned short* wqd_h  = (unsigned short*)alloc((size_t)512 * 384 * 2);
    unsigned short* wqd_l  = (unsigned short*)alloc((size_t)512 * 384 * 2);
    unsigned short* wkvu_h = (unsigned short*)alloc((size_t)256 * 1024 * 2);
    unsigned short* wkvu_l = (unsigned short*)alloc((size_t)256 * 1024 * 2);
    unsigned short* wqu_h  = (unsigned short*)alloc((size_t)384 * 768 * 2);
    unsigned short* wqu_l  = (unsigned short*)alloc((size_t)384 * 768 * 2);
    unsigned short* wo_h   = (unsigned short*)alloc((size_t)512 * 512 * 2);
    unsigned short* wffi_h = (unsigned short*)alloc((size_t)512 * 3072 * 2);
    unsigned short* wffo_h = (unsigned short*)alloc((size_t)1536 * 512 * 2);
    unsigned short* h_hi   = (unsigned short*)alloc((size_t)NM * 512 * 2);
    unsigned short* h_lo   = (unsigned short*)alloc((size_t)NM * 512 * 2);
    // blockCQ : ckv, qd — aliased later by x2 (x2 written after both are dead)
    char* cq0 = p;
    float* ckv = (float*)alloc((size_t)NM * 288 * 4);
    float* qd  = (float*)alloc((size_t)NM * 384 * 4);
    float* x2  = (float*)cq0;
    // blockNorm : ckvn/qdn/o_n/h2 — act aliases the front (all dead before swiglu writes)
    char* nb0 = p;
    unsigned short* ckvn_h = (unsigned short*)alloc((size_t)NM * 256 * 2);
    unsigned short* ckvn_l = (unsigned short*)alloc((size_t)NM * 256 * 2);
    unsigned short* qdn_h  = (unsigned short*)alloc((size_t)NM * 384 * 2);
    unsigned short* qdn_l  = (unsigned short*)alloc((size_t)NM * 384 * 2);
    unsigned short* o_n    = (unsigned short*)alloc((size_t)NM * 512 * 2);
    unsigned short* h2     = (unsigned short*)alloc((size_t)NM * 512 * 2);
    unsigned short* act    = (unsigned short*)nb0;
    // kvf + attention region — uv aliases from kvf onward (all dead before ffi writes uv)
    char* r0 = p;
    float* kvf = (float*)alloc((size_t)NM * 1024 * 4);
    float* qff = (float*)alloc((size_t)NM * 768 * 4);
    _Float16* qgh = (_Float16*)alloc((size_t)NB * H2N * NS_PAD * 64 * 2);
    _Float16* qgl = (_Float16*)alloc((size_t)NB * H2N * NS_PAD * 64 * 2);
    _Float16* kgh = (_Float16*)alloc((size_t)NB * H2N * NS_PAD * 64 * 2);
    _Float16* kgl = (_Float16*)alloc((size_t)NB * H2N * NS_PAD * 64 * 2);
    _Float16* vt  = (_Float16*)alloc((size_t)NB * NH * 64 * NS_PAD * 2);
    float* P4     = (float*)alloc((size_t)NB * NH * SEQN * 64 * 4);
    float* uv     = (float*)r0;
    float* lamv   = (float*)alloc(256);

    auto T = [&](const float* w, unsigned short* hi_, unsigned short* lo_, int K, int N) {
        dim3 g((K + 31) / 32, (N + 31) / 32);
        transpose_split<<<g, 256, 0, stream>>>(w, hi_, lo_, K, N);
    };
    T(Wkvd, wkvd_h, wkvd_l, 512, 288);
    T(Wqd,  wqd_h,  wqd_l,  512, 384);
    T(Wkvu, wkvu_h, wkvu_l, 256, 1024);
    T(Wqu,  wqu_h,  wqu_l,  384, 768);
    T(Wo,   wo_h,   nullptr, 512, 512);
    T(Wffi, wffi_h, nullptr, 512, 3072);
    T(Wffo, wffo_h, nullptr, 1536, 512);
    lam_kernel<<<1, 64, 0, stream>>>(lq1, lk1, lq2, lk2, lamv);

    rmsnorm_k<<<NM, 256, 0, stream>>>(x, n1w, h_hi, h_lo, 512, 512, EPS1);

    const int GX = (NM + 63) / 64;
    gemm_x3<<<dim3(GX, (288 + 63) / 64), 256, 0, stream>>>(h_hi, h_lo, wkvd_h, wkvd_l, ckv, NM, 288, 512);
    gemm_x3<<<dim3(GX, (384 + 63) / 64), 256, 0, stream>>>(h_hi, h_lo, wqd_h, wqd_l, qd, NM, 384, 512);

    rmsnorm_k<<<NM, 256, 0, stream>>>(ckv, kvnw, ckvn_h, ckvn_l, 288, 256, EPS1);
    rmsnorm_k<<<NM, 256, 0, stream>>>(qd, qnw, qdn_h, qdn_l, 384, 384, EPS1);

    gemm_x3<<<dim3(GX, 1024 / 64), 256, 0, stream>>>(ckvn_h, ckvn_l, wkvu_h, wkvu_l, kvf, NM, 1024, 256);
    gemm_x3<<<dim3(GX, 768 / 64), 256, 0, stream>>>(qdn_h, qdn_l, wqu_h, wqu_l, qff, NM, 768, 384);

    {
        size_t total = (size_t)NB * H2N * NS_PAD * 32;
        assemble2<<<dim3((unsigned)((total + 255) / 256)), 256, 0, stream>>>(
            qff, kvf, ckv, freqs, qgh, qgl, kgh, kgl);
    }
    vtrans<<<dim3(NS_PAD / 64, NB * NH), 256, 0, stream>>>(kvf, vt);
    p4sum<<<dim3(NB * NH), 64, 0, stream>>>(kvf, P4);

    flash_attn<<<dim3((NS + 63) / 64, NH, NB), 256, 0, stream>>>(
        qgh, qgl, kgh, kgl, vt, kvf, P4, lamv, hnw, o_n);

    gemm_single<<<dim3(GX, 512 / 64), 256, 0, stream>>>(o_n, wo_h, x2, x, NM, 512, 512);
    rmsnorm_k<<<NM, 256, 0, stream>>>(x2, n2w, h2, nullptr, 512, 512, EPS1);
    gemm_single<<<dim3(GX, 3072 / 64), 256, 0, stream>>>(h2, wffi_h, uv, nullptr, NM, 3072, 512);
    {
        size_t total = (size_t)NM * DFF;
        swiglu_k<<<dim3((unsigned)((total + 255) / 256)), 256, 0, stream>>>(uv, act);
    }
    gemm_single<<<dim3(GX, 512 / 64), 256, 0, stream>>>(act, wffo_h, out, x2, NM, 512, 1536);
}

// Round 5
// 330.987 us; speedup vs baseline: 15.7417x; 1.2247x over previous
//
#include <hip/hip_runtime.h>

#define NB 2
#define SEQN 384
#define NS 1537
#define NS_PAD 1600
#define NH 8
#define H2N 16
#define NM (NB*NS)
#define DFF 1536
#define EPS1 1.1920929e-07f
#define SCAL (1.0f/48.0f)
#define SC2 (SCAL * 1.4426950408889634f)   // SCAL * log2(e), for exp2

typedef __bf16 bf16x8 __attribute__((ext_vector_type(8)));
typedef _Float16 f16x8 __attribute__((ext_vector_type(8)));
typedef float f32x4 __attribute__((ext_vector_type(4)));

__device__ __forceinline__ unsigned short f2bf(float f) {
    unsigned int u = __builtin_bit_cast(unsigned int, f);
    u += 0x7FFFu + ((u >> 16) & 1u);
    return (unsigned short)(u >> 16);
}
__device__ __forceinline__ float bf2f(unsigned short h) {
    unsigned int u = ((unsigned int)h) << 16;
    return __builtin_bit_cast(float, u);
}

// ---------------- transpose weights (KxN f32 -> NxK bf16 hi[/lo]) ----------------
__global__ void transpose_split(const float* __restrict__ w, unsigned short* __restrict__ hi,
                                unsigned short* __restrict__ lo, int K, int N) {
    __shared__ float tile[32][33];
    int k0 = blockIdx.x * 32, n0 = blockIdx.y * 32;
    int tx = threadIdx.x & 31, ty4 = (threadIdx.x >> 5) * 4;
    for (int i = 0; i < 4; i++) {
        int k = k0 + ty4 + i, n = n0 + tx;
        tile[ty4 + i][tx] = (k < K && n < N) ? w[(size_t)k * N + n] : 0.f;
    }
    __syncthreads();
    for (int i = 0; i < 4; i++) {
        int n = n0 + ty4 + i, k = k0 + tx;
        if (n < N && k < K) {
            float v = tile[tx][ty4 + i];
            unsigned short hb = f2bf(v);
            size_t o = (size_t)n * K + k;
            hi[o] = hb;
            if (lo) lo[o] = f2bf(v - bf2f(hb));
        }
    }
}

// ---------------- lambda scalar ----------------
__global__ void lam_kernel(const float* q1, const float* k1, const float* q2, const float* k2,
                           float* out) {
    int t = threadIdx.x;
    float p1 = 0.f, p2 = 0.f;
    if (t < 32) { p1 = q1[t] * k1[t]; p2 = q2[t] * k2[t]; }
    for (int o = 1; o < 32; o <<= 1) { p1 += __shfl_xor(p1, o); p2 += __shfl_xor(p2, o); }
    if (t == 0) out[0] = expf(p1) - expf(p2) + 0.2f;
}

// ---------------- rmsnorm (f32 in, bf16 hi[/lo] out) ----------------
__global__ __launch_bounds__(256) void rmsnorm_k(const float* __restrict__ in,
    const float* __restrict__ w, unsigned short* __restrict__ hi, unsigned short* __restrict__ lo,
    int in_stride, int C, float eps) {
    int row = blockIdx.x;
    const float* x = in + (size_t)row * in_stride;
    float ss = 0.f;
    for (int j = threadIdx.x; j < C; j += 256) { float v = x[j]; ss += v * v; }
    for (int o = 1; o < 64; o <<= 1) ss += __shfl_xor(ss, o);
    __shared__ float red[4];
    if ((threadIdx.x & 63) == 0) red[threadIdx.x >> 6] = ss;
    __syncthreads();
    ss = red[0] + red[1] + red[2] + red[3];
    float rs = rsqrtf(ss / (float)C + eps);
    for (int j = threadIdx.x; j < C; j += 256) {
        float y = x[j] * rs * w[j];
        unsigned short hb = f2bf(y);
        hi[(size_t)row * C + j] = hb;
        if (lo) lo[(size_t)row * C + j] = f2bf(y - bf2f(hb));
    }
}

// ------- single-bf16 GEMM, 128x64 tile, wave=64x32: C = A(MxK) * Bt(NxK)^T [+res] -------
__global__ __launch_bounds__(256) void gemm_single(const unsigned short* __restrict__ A,
    const unsigned short* __restrict__ Bt, float* __restrict__ C_, const float* __restrict__ res,
    int M, int N, int K) {
    __shared__ unsigned short As[128][32];
    __shared__ unsigned short Bs[64][32];
    int m0 = blockIdx.x * 128, n0 = blockIdx.y * 64;
    int tid = threadIdx.x;
    int lane = tid & 63, wid = tid >> 6;
    int wr = wid >> 1, wc = wid & 1;
    int r = lane & 15, g = lane >> 4;
    int lrow = tid >> 2, lk = (tid & 3) * 8;
    f32x4 acc[4][2] = {};
    int ar0 = m0 + lrow, ar1 = m0 + 64 + lrow, brow = n0 + lrow;
    bool a0ok = ar0 < M, a1ok = ar1 < M, bok = brow < N;
    size_t a0off = (size_t)ar0 * K + lk, a1off = (size_t)ar1 * K + lk, boff = (size_t)brow * K + lk;
    for (int k0 = 0; k0 < K; k0 += 32) {
        uint4 av0 = {0,0,0,0}, av1 = {0,0,0,0}, bv = {0,0,0,0};
        if (a0ok) av0 = *(const uint4*)(A + a0off + k0);
        if (a1ok) av1 = *(const uint4*)(A + a1off + k0);
        if (bok)  bv  = *(const uint4*)(Bt + boff + k0);
        __syncthreads();
        *(uint4*)&As[lrow][lk] = av0;
        *(uint4*)&As[64 + lrow][lk] = av1;
        *(uint4*)&Bs[lrow][lk] = bv;
        __syncthreads();
        bf16x8 a[4], bb[2];
        #pragma unroll
        for (int i = 0; i < 4; i++) a[i] = *(const bf16x8*)&As[wr * 64 + i * 16 + r][g * 8];
        #pragma unroll
        for (int j = 0; j < 2; j++) bb[j] = *(const bf16x8*)&Bs[wc * 32 + j * 16 + r][g * 8];
        #pragma unroll
        for (int i = 0; i < 4; i++)
            #pragma unroll
            for (int j = 0; j < 2; j++)
                acc[i][j] = __builtin_amdgcn_mfma_f32_16x16x32_bf16(a[i], bb[j], acc[i][j], 0, 0, 0);
    }
    #pragma unroll
    for (int i = 0; i < 4; i++)
        #pragma unroll
        for (int j = 0; j < 2; j++) {
            int col = n0 + wc * 32 + j * 16 + r;
            if (col >= N) continue;
            #pragma unroll
            for (int e = 0; e < 4; e++) {
                int row = m0 + wr * 64 + i * 16 + g * 4 + e;
                if (row >= M) continue;
                float v = acc[i][j][e];
                if (res) v += res[(size_t)row * N + col];
                C_[(size_t)row * N + col] = v;
            }
        }
}

// ------- split-bf16 (hi+lo, 3xMFMA) GEMM, 128x64 tile: near-fp32 precision -------
__global__ __launch_bounds__(256) void gemm_x3(const unsigned short* __restrict__ Ah,
    const unsigned short* __restrict__ Al, const unsigned short* __restrict__ Bh,
    const unsigned short* __restrict__ Bl, float* __restrict__ C_, int M, int N, int K) {
    __shared__ unsigned short AsH[128][32], AsL[128][32], BsH[64][32], BsL[64][32];
    int m0 = blockIdx.x * 128, n0 = blockIdx.y * 64;
    int tid = threadIdx.x;
    int lane = tid & 63, wid = tid >> 6;
    int wr = wid >> 1, wc = wid & 1;
    int r = lane & 15, g = lane >> 4;
    int lrow = tid >> 2, lk = (tid & 3) * 8;
    f32x4 acc[4][2] = {};
    int ar0 = m0 + lrow, ar1 = m0 + 64 + lrow, brow = n0 + lrow;
    bool a0ok = ar0 < M, a1ok = ar1 < M, bok = brow < N;
    size_t a0off = (size_t)ar0 * K + lk, a1off = (size_t)ar1 * K + lk, boff = (size_t)brow * K + lk;
    for (int k0 = 0; k0 < K; k0 += 32) {
        uint4 ah0 = {0,0,0,0}, al0 = {0,0,0,0}, ah1 = {0,0,0,0}, al1 = {0,0,0,0};
        uint4 bh0 = {0,0,0,0}, bl0 = {0,0,0,0};
        if (a0ok) { ah0 = *(const uint4*)(Ah + a0off + k0); al0 = *(const uint4*)(Al + a0off + k0); }
        if (a1ok) { ah1 = *(const uint4*)(Ah + a1off + k0); al1 = *(const uint4*)(Al + a1off + k0); }
        if (bok)  { bh0 = *(const uint4*)(Bh + boff + k0);  bl0 = *(const uint4*)(Bl + boff + k0); }
        __syncthreads();
        *(uint4*)&AsH[lrow][lk] = ah0; *(uint4*)&AsH[64 + lrow][lk] = ah1;
        *(uint4*)&AsL[lrow][lk] = al0; *(uint4*)&AsL[64 + lrow][lk] = al1;
        *(uint4*)&BsH[lrow][lk] = bh0; *(uint4*)&BsL[lrow][lk] = bl0;
        __syncthreads();
        bf16x8 ah[4], al[4], bh[2], bl[2];
        #pragma unroll
        for (int i = 0; i < 4; i++) {
            ah[i] = *(const bf16x8*)&AsH[wr * 64 + i * 16 + r][g * 8];
            al[i] = *(const bf16x8*)&AsL[wr * 64 + i * 16 + r][g * 8];
        }
        #pragma unroll
        for (int j = 0; j < 2; j++) {
            bh[j] = *(const bf16x8*)&BsH[wc * 32 + j * 16 + r][g * 8];
            bl[j] = *(const bf16x8*)&BsL[wc * 32 + j * 16 + r][g * 8];
        }
        #pragma unroll
        for (int i = 0; i < 4; i++)
            #pragma unroll
            for (int j = 0; j < 2; j++) {
                acc[i][j] = __builtin_amdgcn_mfma_f32_16x16x32_bf16(al[i], bh[j], acc[i][j], 0, 0, 0);
                acc[i][j] = __builtin_amdgcn_mfma_f32_16x16x32_bf16(ah[i], bl[j], acc[i][j], 0, 0, 0);
                acc[i][j] = __builtin_amdgcn_mfma_f32_16x16x32_bf16(ah[i], bh[j], acc[i][j], 0, 0, 0);
            }
    }
    #pragma unroll
    for (int i = 0; i < 4; i++)
        #pragma unroll
        for (int j = 0; j < 2; j++) {
            int col = n0 + wc * 32 + j * 16 + r;
            if (col >= N) continue;
            #pragma unroll
            for (int e = 0; e < 4; e++) {
                int row = m0 + wr * 64 + i * 16 + g * 4 + e;
                if (row < M) C_[(size_t)row * N + col] = acc[i][j][e];
            }
        }
}

// ---------------- assemble q/k heads (f16 hi/lo, RoPE applied, padded 48->64) ------
// layout: each of qgh/qgl/kgh/kgl : [ (b*8+h)*2+sub ][ NS_PAD ][ 64 ] f16
__global__ void assemble2(const float* __restrict__ qf_, const float* __restrict__ kvf,
    const float* __restrict__ ckv, const float* __restrict__ freqs,
    _Float16* __restrict__ qgh, _Float16* __restrict__ qgl,
    _Float16* __restrict__ kgh, _Float16* __restrict__ kgl) {
    size_t idx = (size_t)blockIdx.x * 256 + threadIdx.x;
    const size_t total = (size_t)NB * H2N * NS_PAD * 32;
    if (idx >= total) return;
    int j2 = (int)(idx & 31);
    size_t t = idx >> 5;
    int s = (int)(t % NS_PAD); size_t r = t / NS_PAD;
    int sub = (int)(r & 1); r >>= 1;
    int h = (int)(r & 7); int b = (int)(r >> 3);
    float2 qv = make_float2(0.f, 0.f), kv2 = make_float2(0.f, 0.f);
    if (s < NS && j2 < 24) {
        size_t bs = (size_t)b * NS + s;
        if (j2 < 16) {
            const float* qp = qf_ + bs * 768 + h * 96 + sub * 32 + j2 * 2;
            qv = make_float2(qp[0], qp[1]);
            const float* kp = kvf + bs * 1024 + h * 128 + sub * 32 + j2 * 2;
            kv2 = make_float2(kp[0], kp[1]);
        } else {
            int i = j2 - 16;
            const float* qp = qf_ + bs * 768 + h * 96 + 64 + sub * 16 + 2 * i;
            float xr = qp[0], xi = qp[1];
            const float* kp = ckv + bs * 288 + 256 + sub * 16 + 2 * i;
            float yr = kp[0], yi = kp[1];
            if (s == 0) {
                qv = make_float2(xr, xi);
                kv2 = make_float2(yr, yi);
            } else {
                int pos = (s - 1) % SEQN;
                float c = freqs[pos * 16 + 2 * i], sn = freqs[pos * 16 + 2 * i + 1];
                qv = make_float2(xr * c - xi * sn, xr * sn + xi * c);
                kv2 = make_float2(yr * c - yi * sn, yr * sn + yi * c);
            }
        }
    }
    _Float16 qx = (_Float16)qv.x, qy = (_Float16)qv.y;
    _Float16 kx = (_Float16)kv2.x, ky = (_Float16)kv2.y;
    qgh[idx * 2] = qx; qgh[idx * 2 + 1] = qy;
    kgh[idx * 2] = kx; kgh[idx * 2 + 1] = ky;
    qgl[idx * 2] = (_Float16)(qv.x - (float)qx); qgl[idx * 2 + 1] = (_Float16)(qv.y - (float)qy);
    kgl[idx * 2] = (_Float16)(kv2.x - (float)kx); kgl[idx * 2 + 1] = (_Float16)(kv2.y - (float)ky);
}

// ---------------- V transpose: kvf -> vt [ (b*8+h)*64 + d ][ NS_PAD ] f16 ----------------
__global__ __launch_bounds__(256) void vtrans(const float* __restrict__ kvf,
                                              _Float16* __restrict__ vt) {
    __shared__ float tile[64][65];
    int k0 = blockIdx.x * 64;
    int b = blockIdx.y >> 3, h = blockIdx.y & 7;
    int tid = threadIdx.x;
    int row = tid >> 2, cq = (tid & 3) * 16;
    for (int i = 0; i < 16; i++) {
        int key = k0 + row;
        tile[row][cq + i] = (key < NS)
            ? kvf[((size_t)(b * NS + key)) * 1024 + h * 128 + 64 + cq + i] : 0.f;
    }
    __syncthreads();
    int d = tid >> 2, kq = (tid & 3) * 16;
    for (int i = 0; i < 16; i++)
        vt[((size_t)((b * 8 + h) * 64 + d)) * NS_PAD + k0 + kq + i] = (_Float16)tile[kq + i][d];
}

// ---------------- S4: per-position 4-chunk v-sum (parallel) ----------------
__global__ __launch_bounds__(256) void sum4_k(const float* __restrict__ kvf,
                                              float* __restrict__ S4) {
    int bh = blockIdx.x; int b = bh >> 3, h = bh & 7;
    int p0 = blockIdx.y * 64;
    int t = threadIdx.x;
    int d = t & 63, psub = t >> 6;
    for (int i = 0; i < 16; i++) {
        int p = p0 + psub + i * 4;
        float s = 0.f;
        #pragma unroll
        for (int c = 0; c < 4; c++)
            s += kvf[((size_t)(b * NS + 1 + c * SEQN + p)) * 1024 + h * 128 + 64 + d];
        S4[((size_t)bh * SEQN + p) * 64 + d] = s;
    }
}

// ---------------- prefix over positions ----------------
__global__ void prefix_k(const float* __restrict__ S4, float* __restrict__ P4) {
    int bh = blockIdx.x; int d = threadIdx.x;
    float acc = 0.f;
    for (int p = 0; p < SEQN; p++) {
        acc += S4[((size_t)bh * SEQN + p) * 64 + d];
        P4[((size_t)bh * SEQN + p) * 64 + d] = acc;
    }
}

// ------- flash differential attention (no-max softmax, deferred reductions) -------
__global__ __launch_bounds__(256) void flash_attn(
    const _Float16* __restrict__ qgh, const _Float16* __restrict__ qgl,
    const _Float16* __restrict__ kgh, const _Float16* __restrict__ kgl,
    const _Float16* __restrict__ vt,
    const float* __restrict__ kvf, const float* __restrict__ P4,
    const float* __restrict__ lamp, const float* __restrict__ hw,
    unsigned short* __restrict__ o_n) {
    __shared__ _Float16 Ksh[2][64][72];
    __shared__ _Float16 Ksl[2][64][72];
    __shared__ _Float16 Vt[64][72];
    __shared__ _Float16 Pl[4][16][72];
    const int tile = blockIdx.x, h = blockIdx.y, b = blockIdx.z;
    const int qs0 = tile * 64;
    const int tid = threadIdx.x;
    const int wave = tid >> 6, lane = tid & 63;
    const int r = lane & 15, g = lane >> 4;
    const int qrow = qs0 + wave * 16;
    const size_t sh0 = (size_t)((b * 8 + h) * 2);

    f16x8 qfh[2][2], qfl[2][2];
    #pragma unroll
    for (int sub = 0; sub < 2; sub++)
        #pragma unroll
        for (int ks = 0; ks < 2; ks++) {
            size_t off = ((sh0 + sub) * NS_PAD + qrow + r) * 64 + ks * 32 + g * 8;
            qfh[sub][ks] = *(const f16x8*)(qgh + off);
            qfl[sub][ks] = *(const f16x8*)(qgl + off);
        }

    // bounded scores (|a| <~ 0.3): no max tracking needed; plain sums, reduced once at end
    float z0p[4] = {0.f,0.f,0.f,0.f}, g0p[4] = {0.f,0.f,0.f,0.f}, z1p[4] = {0.f,0.f,0.f,0.f};
    f32x4 O0[4], O1[4];
    #pragma unroll
    for (int e = 0; e < 4; e++) { O0[e] = (f32x4){0.f,0.f,0.f,0.f}; O1[e] = (f32x4){0.f,0.f,0.f,0.f}; }
    int qpos[4];
    #pragma unroll
    for (int e = 0; e < 4; e++) {
        int q = qrow + g * 4 + e;
        qpos[e] = (q == 0) ? -1 : (q - 1) % SEQN;
    }
    int lo = qs0 < 1 ? 1 : qs0;
    int hi = qs0 + 63 < NS - 1 ? qs0 + 63 : NS - 1;
    int maxpos = ((lo - 1) / SEQN != (hi - 1) / SEQN) ? (SEQN - 1) : (hi - 1) % SEQN;

    for (int c = 0; c < 4; c++) {
        int nb = (c == 0) ? ((maxpos + 2 + 63) >> 6) : ((maxpos + 1 + 63) >> 6);
        int kstart = (c == 0) ? 0 : (c * SEQN + 1);
        int cbase = c * SEQN + 1;
        for (int j = 0; j < nb; j++) {
            int kbase = kstart + j * 64;
            __syncthreads();
            #pragma unroll
            for (int i = 0; i < 4; i++) {
                int chunk = i * 256 + tid;
                int arr = chunk >> 9;
                int cc = chunk & 511;
                int row = cc >> 3, c8 = (cc & 7) * 8;
                size_t goff = ((sh0 + arr) * NS_PAD + kbase + row) * 64 + c8;
                *(uint4*)&Ksh[arr][row][c8] = *(const uint4*)(kgh + goff);
                *(uint4*)&Ksl[arr][row][c8] = *(const uint4*)(kgl + goff);
            }
            #pragma unroll
            for (int i = 0; i < 2; i++) {
                int cc = i * 256 + tid;
                int d = cc >> 3, c8 = (cc & 7) * 8;
                *(uint4*)&Vt[d][c8] =
                    *(const uint4*)(vt + ((size_t)((b * 8 + h) * 64 + d)) * NS_PAD + kbase + c8);
            }
            __syncthreads();

            f16x8 bv[4][2];
            #pragma unroll
            for (int dt = 0; dt < 4; dt++)
                #pragma unroll
                for (int ks = 0; ks < 2; ks++)
                    bv[dt][ks] = *(const f16x8*)&Vt[dt * 16 + r][ks * 32 + g * 8];

            // mask bits, sub-independent: hoisted
            bool um[4][4];
            #pragma unroll
            for (int t4 = 0; t4 < 4; t4++) {
                int kk2 = kbase + t4 * 16 + r;
                int rel = kk2 - cbase;
                #pragma unroll
                for (int e = 0; e < 4; e++)
                    um[e][t4] = (kk2 == 0) ||
                                ((unsigned)rel < (unsigned)SEQN && rel <= qpos[e]);
            }

            #pragma unroll
            for (int sub = 0; sub < 2; sub++) {
                f32x4 acc[4];
                #pragma unroll
                for (int t4 = 0; t4 < 4; t4++) acc[t4] = (f32x4){0.f,0.f,0.f,0.f};
                #pragma unroll
                for (int t4 = 0; t4 < 4; t4++)
                    #pragma unroll
                    for (int ks = 0; ks < 2; ks++) {
                        f16x8 bkh = *(const f16x8*)&Ksh[sub][t4 * 16 + r][ks * 32 + g * 8];
                        f16x8 bkl = *(const f16x8*)&Ksl[sub][t4 * 16 + r][ks * 32 + g * 8];
                        acc[t4] = __builtin_amdgcn_mfma_f32_16x16x32_f16(qfl[sub][ks], bkh, acc[t4], 0, 0, 0);
                        acc[t4] = __builtin_amdgcn_mfma_f32_16x16x32_f16(qfh[sub][ks], bkl, acc[t4], 0, 0, 0);
                        acc[t4] = __builtin_amdgcn_mfma_f32_16x16x32_f16(qfh[sub][ks], bkh, acc[t4], 0, 0, 0);
                    }
                #pragma unroll
                for (int e = 0; e < 4; e++) {
                    #pragma unroll
                    for (int t4 = 0; t4 < 4; t4++) {
                        float a = acc[t4][e];
                        float ef = exp2f(fabsf(a) * SC2);      // exp(|a|*SCAL)
                        float ev = um[e][t4] ? ef : 0.f;
                        float pvv = copysignf(ev, a);           // sign(a)*ev
                        if (sub == 0) { z0p[e] += ev; g0p[e] += pvv; }
                        else          { z1p[e] += ev; }
                        Pl[wave][g * 4 + e][t4 * 16 + r] = (_Float16)pvv;
                    }
                }
                __builtin_amdgcn_wave_barrier();
                f16x8 pa0 = *(const f16x8*)&Pl[wave][r][g * 8];
                f16x8 pa1 = *(const f16x8*)&Pl[wave][r][32 + g * 8];
                #pragma unroll
                for (int dt = 0; dt < 4; dt++) {
                    if (sub == 0) {
                        O0[dt] = __builtin_amdgcn_mfma_f32_16x16x32_f16(pa0, bv[dt][0], O0[dt], 0, 0, 0);
                        O0[dt] = __builtin_amdgcn_mfma_f32_16x16x32_f16(pa1, bv[dt][1], O0[dt], 0, 0, 0);
                    } else {
                        O1[dt] = __builtin_amdgcn_mfma_f32_16x16x32_f16(pa0, bv[dt][0], O1[dt], 0, 0, 0);
                        O1[dt] = __builtin_amdgcn_mfma_f32_16x16x32_f16(pa1, bv[dt][1], O1[dt], 0, 0, 0);
                    }
                }
            }
        }
    }

    // epilogue: single deferred reduction, combine + G-term, head rmsnorm, store
    float lam = lamp[0];
    float v0d[4], hwd[4];
    #pragma unroll
    for (int dt = 0; dt < 4; dt++) {
        int d = dt * 16 + r;
        v0d[dt] = kvf[((size_t)(b * NS)) * 1024 + h * 128 + 64 + d];
        hwd[dt] = hw[d];
    }
    #pragma unroll
    for (int e = 0; e < 4; e++) {
        float z0 = z0p[e], g0 = g0p[e], z1 = z1p[e];
        #pragma unroll
        for (int o = 1; o < 16; o <<= 1) {
            z0 += __shfl_xor(z0, o); g0 += __shfl_xor(g0, o); z1 += __shfl_xor(z1, o);
        }
        int q = qrow + g * 4 + e;
        if (q >= NS) continue;
        float iz0 = 1.f / z0;
        float l1 = lam / z1;
        float Gl = lam * g0 * iz0 * (1.f / (float)NS);
        float of[4]; float ss = 0.f;
        #pragma unroll
        for (int dt = 0; dt < 4; dt++) {
            float vs = v0d[dt];
            if (qpos[e] >= 0)
                vs += P4[((size_t)(b * 8 + h) * SEQN + qpos[e]) * 64 + dt * 16 + r];
            float o = O0[dt][e] * iz0 - O1[dt][e] * l1 + Gl * vs;
            of[dt] = o; ss += o * o;
        }
        ss += __shfl_xor(ss, 1); ss += __shfl_xor(ss, 2);
        ss += __shfl_xor(ss, 4); ss += __shfl_xor(ss, 8);
        float rs = rsqrtf(ss / 64.f + 1e-5f);
        #pragma unroll
        for (int dt = 0; dt < 4; dt++)
            o_n[((size_t)(b * NS + q)) * 512 + h * 64 + dt * 16 + r] = f2bf(of[dt] * rs * hwd[dt]);
    }
}

// ---------------- swiglu: uv(M x 3072) -> act bf16 (M x 1536) ----------------
__global__ void swiglu_k(const float* __restrict__ uv, unsigned short* __restrict__ act) {
    size_t idx = (size_t)blockIdx.x * 256 + threadIdx.x;
    if (idx >= (size_t)NM * DFF) return;
    size_t mrow = idx / DFF; int j = (int)(idx % DFF);
    float u = uv[mrow * (2 * DFF) + j];
    float gg = uv[mrow * (2 * DFF) + DFF + j];
    float sg = gg / (1.f + __expf(-gg));
    act[idx] = f2bf(u * sg);
}

// ---------------- host ----------------
extern "C" void kernel_launch(void* const* d_in, const int* in_sizes, int n_in,
                              void* d_out, int out_size, void* d_ws, size_t ws_size,
                              hipStream_t stream) {
    (void)in_sizes; (void)n_in; (void)out_size; (void)ws_size;
    const float* x    = (const float*)d_in[0];
    const float* freqs= (const float*)d_in[1];
    const float* Wkvd = (const float*)d_in[2];
    const float* Wqd  = (const float*)d_in[3];
    const float* Wkvu = (const float*)d_in[4];
    const float* Wqu  = (const float*)d_in[5];
    const float* kvnw = (const float*)d_in[6];
    const float* qnw  = (const float*)d_in[7];
    const float* Wo   = (const float*)d_in[8];
    const float* lq1  = (const float*)d_in[9];
    const float* lk1  = (const float*)d_in[10];
    const float* lq2  = (const float*)d_in[11];
    const float* lk2  = (const float*)d_in[12];
    const float* hnw  = (const float*)d_in[13];
    const float* n1w  = (const float*)d_in[14];
    const float* n2w  = (const float*)d_in[15];
    const float* Wffi = (const float*)d_in[16];
    const float* Wffo = (const float*)d_in[17];
    float* out = (float*)d_out;

    char* p = (char*)d_ws;
    auto alloc = [&](size_t nbytes) -> char* {
        char* r = p; p += (nbytes + 255) & ~(size_t)255; return r;
    };
    // weights
    unsigned short* wkvd_h = (unsigned short*)alloc((size_t)512 * 288 * 2);
    unsigned short* wkvd_l = (unsigned short*)alloc((size_t)512 * 288 * 2);
    unsigned short* wqd_h  = (unsigned short*)alloc((size_t)512 * 384 * 2);
    unsigned short* wqd_l  = (unsigned short*)alloc((size_t)512 * 384 * 2);
    unsigned short* wkvu_h = (unsigned short*)alloc((size_t)256 * 1024 * 2);
    unsigned short* wkvu_l = (unsigned short*)alloc((size_t)256 * 1024 * 2);
    unsigned short* wqu_h  = (unsigned short*)alloc((size_t)384 * 768 * 2);
    unsigned short* wqu_l  = (unsigned short*)alloc((size_t)384 * 768 * 2);
    unsigned short* wo_h   = (unsigned short*)alloc((size_t)512 * 512 * 2);
    unsigned short* wffi_h = (unsigned short*)alloc((size_t)512 * 3072 * 2);
    unsigned short* wffo_h = (unsigned short*)alloc((size_t)1536 * 512 * 2);
    unsigned short* h_hi   = (unsigned short*)alloc((size_t)NM * 512 * 2);
    unsigned short* h_lo   = (unsigned short*)alloc((size_t)NM * 512 * 2);
    // blockCQ : ckv, qd — aliased later by x2
    char* cq0 = p;
    float* ckv = (float*)alloc((size_t)NM * 288 * 4);
    float* qd  = (float*)alloc((size_t)NM * 384 * 4);
    float* x2  = (float*)cq0;
    // blockNorm : ckvn/qdn/o_n/h2 — act aliases the front
    char* nb0 = p;
    unsigned short* ckvn_h = (unsigned short*)alloc((size_t)NM * 256 * 2);
    unsigned short* ckvn_l = (unsigned short*)alloc((size_t)NM * 256 * 2);
    unsigned short* qdn_h  = (unsigned short*)alloc((size_t)NM * 384 * 2);
    unsigned short* qdn_l  = (unsigned short*)alloc((size_t)NM * 384 * 2);
    unsigned short* o_n    = (unsigned short*)alloc((size_t)NM * 512 * 2);
    unsigned short* h2     = (unsigned short*)alloc((size_t)NM * 512 * 2);
    unsigned short* act    = (unsigned short*)nb0;
    // kvf + attention region — uv aliases from kvf onward
    char* r0 = p;
    float* kvf = (float*)alloc((size_t)NM * 1024 * 4);
    float* qff = (float*)alloc((size_t)NM * 768 * 4);
    _Float16* qgh = (_Float16*)alloc((size_t)NB * H2N * NS_PAD * 64 * 2);
    _Float16* qgl = (_Float16*)alloc((size_t)NB * H2N * NS_PAD * 64 * 2);
    _Float16* kgh = (_Float16*)alloc((size_t)NB * H2N * NS_PAD * 64 * 2);
    _Float16* kgl = (_Float16*)alloc((size_t)NB * H2N * NS_PAD * 64 * 2);
    _Float16* vt  = (_Float16*)alloc((size_t)NB * NH * 64 * NS_PAD * 2);
    float* P4     = (float*)alloc((size_t)NB * NH * SEQN * 64 * 4);
    float* S4     = (float*)alloc((size_t)NB * NH * SEQN * 64 * 4);
    float* uv     = (float*)r0;
    float* lamv   = (float*)alloc(256);

    auto T = [&](const float* w, unsigned short* hi_, unsigned short* lo_, int K, int N) {
        dim3 g((K + 31) / 32, (N + 31) / 32);
        transpose_split<<<g, 256, 0, stream>>>(w, hi_, lo_, K, N);
    };
    T(Wkvd, wkvd_h, wkvd_l, 512, 288);
    T(Wqd,  wqd_h,  wqd_l,  512, 384);
    T(Wkvu, wkvu_h, wkvu_l, 256, 1024);
    T(Wqu,  wqu_h,  wqu_l,  384, 768);
    T(Wo,   wo_h,   nullptr, 512, 512);
    T(Wffi, wffi_h, nullptr, 512, 3072);
    T(Wffo, wffo_h, nullptr, 1536, 512);
    lam_kernel<<<1, 64, 0, stream>>>(lq1, lk1, lq2, lk2, lamv);

    rmsnorm_k<<<NM, 256, 0, stream>>>(x, n1w, h_hi, h_lo, 512, 512, EPS1);

    const int GX = (NM + 127) / 128;
    gemm_x3<<<dim3(GX, (288 + 63) / 64), 256, 0, stream>>>(h_hi, h_lo, wkvd_h, wkvd_l, ckv, NM, 288, 512);
    gemm_x3<<<dim3(GX, (384 + 63) / 64), 256, 0, stream>>>(h_hi, h_lo, wqd_h, wqd_l, qd, NM, 384, 512);

    rmsnorm_k<<<NM, 256, 0, stream>>>(ckv, kvnw, ckvn_h, ckvn_l, 288, 256, EPS1);
    rmsnorm_k<<<NM, 256, 0, stream>>>(qd, qnw, qdn_h, qdn_l, 384, 384, EPS1);

    gemm_x3<<<dim3(GX, 1024 / 64), 256, 0, stream>>>(ckvn_h, ckvn_l, wkvu_h, wkvu_l, kvf, NM, 1024, 256);
    gemm_x3<<<dim3(GX, 768 / 64), 256, 0, stream>>>(qdn_h, qdn_l, wqu_h, wqu_l, qff, NM, 768, 384);

    {
        size_t total = (size_t)NB * H2N * NS_PAD * 32;
        assemble2<<<dim3((unsigned)((total + 255) / 256)), 256, 0, stream>>>(
            qff, kvf, ckv, freqs, qgh, qgl, kgh, kgl);
    }
    vtrans<<<dim3(NS_PAD / 64, NB * NH), 256, 0, stream>>>(kvf, vt);
    sum4_k<<<dim3(NB * NH, SEQN / 64), 256, 0, stream>>>(kvf, S4);
    prefix_k<<<dim3(NB * NH), 64, 0, stream>>>(S4, P4);

    flash_attn<<<dim3((NS + 63) / 64, NH, NB), 256, 0, stream>>>(
        qgh, qgl, kgh, kgl, vt, kvf, P4, lamv, hnw, o_n);

    gemm_single<<<dim3(GX, 512 / 64), 256, 0, stream>>>(o_n, wo_h, x2, x, NM, 512, 512);
    rmsnorm_k<<<NM, 256, 0, stream>>>(x2, n2w, h2, nullptr, 512, 512, EPS1);
    gemm_single<<<dim3(GX, 3072 / 64), 256, 0, stream>>>(h2, wffi_h, uv, nullptr, NM, 3072, 512);
    {
        size_t total = (size_t)NM * DFF;
        swiglu_k<<<dim3((unsigned)((total + 255) / 256)), 256, 0, stream>>>(uv, act);
    }
    gemm_single<<<dim3(GX, 512 / 64), 256, 0, stream>>>(act, wffo_h, out, x2, NM, 512, 1536);
}